// Round 1
// baseline (2906.219 us; speedup 1.0000x reference)
//
#include <hip/hip_runtime.h>

#define NNODE 100000
#define NEDGE 800000
// H = 4, D = 32, H*D = 128, DN = DE = 32, NL = 3

// ---------------------------------------------------------------------------
// CSR build kernels (dst-indexed), run once per call
// ---------------------------------------------------------------------------
__global__ __launch_bounds__(256) void zero_ints(int* __restrict__ a, int* __restrict__ b, int n) {
    int i = blockIdx.x * 256 + threadIdx.x;
    if (i < n) { a[i] = 0; b[i] = 0; }
}

__global__ __launch_bounds__(256) void count_dst(const int* __restrict__ dst, int* __restrict__ counts) {
    int e = blockIdx.x * 256 + threadIdx.x;
    if (e < NEDGE) atomicAdd(&counts[dst[e]], 1);
}

// chunk = 1024 elements per block (256 thr x 4)
__global__ __launch_bounds__(256) void scan_chunks(const int* __restrict__ counts, int* __restrict__ ro,
                                                   int* __restrict__ bsums, int n) {
    __shared__ int sh[256];
    int base = blockIdx.x * 1024;
    int t = threadIdx.x;
    int v[4];
    int s = 0;
    #pragma unroll
    for (int i = 0; i < 4; i++) {
        int idx = base + t * 4 + i;
        int c = (idx < n) ? counts[idx] : 0;
        v[i] = s; s += c;
    }
    sh[t] = s; __syncthreads();
    for (int off = 1; off < 256; off <<= 1) {
        int x = 0;
        if (t >= off) x = sh[t - off];
        __syncthreads();
        if (t >= off) sh[t] += x;
        __syncthreads();
    }
    int thr_excl = (t > 0) ? sh[t - 1] : 0;
    #pragma unroll
    for (int i = 0; i < 4; i++) {
        int idx = base + t * 4 + i;
        if (idx < n) ro[idx] = thr_excl + v[i];
    }
    if (t == 255) bsums[blockIdx.x] = sh[255];
}

__global__ __launch_bounds__(256) void scan_bsums(int* __restrict__ bsums, int nb) {
    __shared__ int sh[256];
    int t = threadIdx.x;
    int val = (t < nb) ? bsums[t] : 0;
    sh[t] = val; __syncthreads();
    for (int off = 1; off < 256; off <<= 1) {
        int x = 0;
        if (t >= off) x = sh[t - off];
        __syncthreads();
        if (t >= off) sh[t] += x;
        __syncthreads();
    }
    int excl = (t > 0) ? sh[t - 1] : 0;
    if (t < nb) bsums[t] = excl;
}

__global__ __launch_bounds__(256) void scan_add(int* __restrict__ ro, const int* __restrict__ bsums, int n) {
    int i = blockIdx.x * 256 + threadIdx.x;
    if (i < n) ro[i] += bsums[i >> 10];
    if (i == 0) ro[n] = NEDGE;
}

__global__ __launch_bounds__(256) void scatter_edges(const int* __restrict__ dst, const int* __restrict__ ro,
                                                     int* __restrict__ cursor, int* __restrict__ eidx) {
    int e = blockIdx.x * 256 + threadIdx.x;
    if (e < NEDGE) {
        int d = dst[e];
        int pos = atomicAdd(&cursor[d], 1);
        eidx[ro[d] + pos] = e;
    }
}

// ---------------------------------------------------------------------------
// Per-layer kernels
// ---------------------------------------------------------------------------

// f_ni = nf@W_ni, f_nj = nf@W_nj, h = nf@W_node   (one thread per node)
__global__ __launch_bounds__(256) void node_gemm(
    const float* __restrict__ nf,
    const float* __restrict__ Wni, const float* __restrict__ Wnj, const float* __restrict__ Wnode,
    float* __restrict__ f_ni, float* __restrict__ f_nj, float* __restrict__ hmat) {
    int n = blockIdx.x * 256 + threadIdx.x;
    if (n >= NNODE) return;
    float nv[32];
    const float4* nr = (const float4*)(nf + (size_t)n * 32);
    #pragma unroll
    for (int i = 0; i < 8; i++) {
        float4 q = nr[i];
        nv[4 * i] = q.x; nv[4 * i + 1] = q.y; nv[4 * i + 2] = q.z; nv[4 * i + 3] = q.w;
    }
    const float* Ws[3] = {Wni, Wnj, Wnode};
    float* Os[3] = {f_ni, f_nj, hmat};
    for (int m = 0; m < 3; m++) {
        const float* W = Ws[m];
        float* O = Os[m] + (size_t)n * 128;
        for (int h = 0; h < 4; h++) {
            float acc[32];
            #pragma unroll
            for (int j = 0; j < 32; j++) acc[j] = 0.f;
            #pragma unroll
            for (int k = 0; k < 32; k++) {
                float v = nv[k];
                #pragma unroll
                for (int j = 0; j < 32; j++)
                    acc[j] = fmaf(v, W[k * 128 + h * 32 + j], acc[j]);
            }
            #pragma unroll
            for (int j0 = 0; j0 < 8; j0++)
                *(float4*)(O + h * 32 + 4 * j0) =
                    make_float4(acc[4 * j0], acc[4 * j0 + 1], acc[4 * j0 + 2], acc[4 * j0 + 3]);
        }
    }
}

// Per edge: f_fij = ef@W_fij ; f_out = leaky(f_ni[src]+f_nj[dst]+f_fij+bias)
// logits[e][h] = <f_out[h], attn[h]> ; ef_out = mean_h f_out
template <bool WRITE_EF>
__global__ __launch_bounds__(256) void edge_kernel(
    const float* __restrict__ ef_in,
    const int* __restrict__ src, const int* __restrict__ dst,
    const float* __restrict__ f_ni, const float* __restrict__ f_nj,
    const float* __restrict__ Wf,     // 32x128 layer slice
    const float* __restrict__ attn,   // 4x32 layer slice
    const float* __restrict__ bias,   // 128 layer slice
    float* __restrict__ logits,       // E x 4
    float* __restrict__ ef_out) {     // E x 32
    int e = blockIdx.x * 256 + threadIdx.x;
    if (e >= NEDGE) return;
    float efv[32];
    const float4* er = (const float4*)(ef_in + (size_t)e * 32);
    #pragma unroll
    for (int i = 0; i < 8; i++) {
        float4 q = er[i];
        efv[4 * i] = q.x; efv[4 * i + 1] = q.y; efv[4 * i + 2] = q.z; efv[4 * i + 3] = q.w;
    }
    int s = src[e], d = dst[e];
    const float* nir = f_ni + (size_t)s * 128;
    const float* njr = f_nj + (size_t)d * 128;
    float macc[32];
    #pragma unroll
    for (int j = 0; j < 32; j++) macc[j] = 0.f;
    float lg[4];
    #pragma unroll
    for (int h = 0; h < 4; h++) {
        float acc[32];
        #pragma unroll
        for (int j = 0; j < 32; j++) acc[j] = bias[h * 32 + j];
        #pragma unroll
        for (int k = 0; k < 32; k++) {
            float v = efv[k];
            #pragma unroll
            for (int j = 0; j < 32; j++)
                acc[j] = fmaf(v, Wf[k * 128 + h * 32 + j], acc[j]);
        }
        float lgh = 0.f;
        #pragma unroll
        for (int j0 = 0; j0 < 8; j0++) {
            float4 a = *(const float4*)(nir + h * 32 + 4 * j0);
            float4 b = *(const float4*)(njr + h * 32 + 4 * j0);
            float av[4] = {a.x, a.y, a.z, a.w};
            float bv[4] = {b.x, b.y, b.z, b.w};
            #pragma unroll
            for (int q = 0; q < 4; q++) {
                int j = 4 * j0 + q;
                float x = acc[j] + av[q] + bv[q];
                x = (x >= 0.f) ? x : 0.2f * x;
                lgh = fmaf(x, attn[h * 32 + j], lgh);
                macc[j] += x;
            }
        }
        lg[h] = lgh;
    }
    *(float4*)(logits + (size_t)e * 4) = make_float4(lg[0], lg[1], lg[2], lg[3]);
    if (WRITE_EF) {
        float4* eo = (float4*)(ef_out + (size_t)e * 32);
        #pragma unroll
        for (int i = 0; i < 8; i++)
            eo[i] = make_float4(macc[4 * i] * 0.25f, macc[4 * i + 1] * 0.25f,
                                macc[4 * i + 2] * 0.25f, macc[4 * i + 3] * 0.25f);
    }
}

// One wave per dst node. Lane l owns cols l and l+64 of the 128-wide head space.
__global__ __launch_bounds__(256) void aggregate(
    const int* __restrict__ ro, const int* __restrict__ eidx,
    const int* __restrict__ src,
    const float* __restrict__ logits,  // E x 4
    const float* __restrict__ hmat,    // N x 128
    float* __restrict__ nf_out) {      // N x 32
    int wid = (blockIdx.x * 256 + threadIdx.x) >> 6;
    int lane = threadIdx.x & 63;
    if (wid >= NNODE) return;
    int beg = ro[wid], end = ro[wid + 1];
    if (beg == end) {
        if (lane < 32) nf_out[(size_t)wid * 32 + lane] = 0.f;
        return;
    }
    int hA = lane >> 5;  // head of col `lane` (0 or 1); col lane+64 -> head hA+2
    float m1 = -1e30f, m2 = -1e30f;
    for (int i = beg; i < end; i++) {
        int e = eidx[i];
        m1 = fmaxf(m1, logits[(size_t)e * 4 + hA]);
        m2 = fmaxf(m2, logits[(size_t)e * 4 + hA + 2]);
    }
    float den1 = 0.f, den2 = 0.f, acc1 = 0.f, acc2 = 0.f;
    for (int i = beg; i < end; i++) {
        int e = eidx[i];
        int s = src[e];
        float l1 = logits[(size_t)e * 4 + hA];
        float l2 = logits[(size_t)e * 4 + hA + 2];
        float a1 = __expf(l1 - m1);
        float a2 = __expf(l2 - m2);
        den1 += a1; den2 += a2;
        const float* hr = hmat + (size_t)s * 128;
        acc1 = fmaf(a1, hr[lane], acc1);
        acc2 = fmaf(a2, hr[lane + 64], acc2);
    }
    float r = acc1 / den1 + acc2 / den2;
    r += __shfl_xor(r, 32, 64);
    if (lane < 32) nf_out[(size_t)wid * 32 + lane] = 0.25f * r;
}

// ---------------------------------------------------------------------------
extern "C" void kernel_launch(void* const* d_in, const int* in_sizes, int n_in,
                              void* d_out, int out_size, void* d_ws, size_t ws_size,
                              hipStream_t stream) {
    const float* nf   = (const float*)d_in[0];
    const float* ef   = (const float*)d_in[1];
    const int*   src  = (const int*)d_in[2];
    const int*   dst  = (const int*)d_in[3];
    const float* Wni  = (const float*)d_in[4];
    const float* Wnj  = (const float*)d_in[5];
    const float* Wfij = (const float*)d_in[6];
    const float* Wnd  = (const float*)d_in[7];
    const float* attn = (const float*)d_in[8];
    const float* bias = (const float*)d_in[9];
    float* out = (float*)d_out;

    char* ws = (char*)d_ws;
    size_t off = 0;
    auto alloc = [&](size_t bytes) {
        void* p = ws + off;
        off += (bytes + 255) & ~(size_t)255;
        return p;
    };
    float* fni    = (float*)alloc((size_t)NNODE * 128 * 4);
    float* fnj    = (float*)alloc((size_t)NNODE * 128 * 4);
    float* hmat   = (float*)alloc((size_t)NNODE * 128 * 4);
    float* efA    = (float*)alloc((size_t)NEDGE * 32 * 4);
    float* logits = (float*)alloc((size_t)NEDGE * 4 * 4);
    float* nfA    = (float*)alloc((size_t)NNODE * 32 * 4);
    int*   counts = (int*)alloc((size_t)NNODE * 4);
    int*   cursor = (int*)alloc((size_t)NNODE * 4);
    int*   ro     = (int*)alloc((size_t)(NNODE + 1) * 4);
    int*   eidx   = (int*)alloc((size_t)NEDGE * 4);
    int*   bsums  = (int*)alloc(1024 * 4);

    const int NB_E = (NEDGE + 255) / 256;          // 3125
    const int NB_N = (NNODE + 255) / 256;          // 391
    const int NB_AGG = (NNODE + 3) / 4;            // 25000 (4 waves/block)
    const int NB_SCAN = (NNODE + 1023) / 1024;     // 98

    // Build dst-CSR once per call
    zero_ints<<<NB_N, 256, 0, stream>>>(counts, cursor, NNODE);
    count_dst<<<NB_E, 256, 0, stream>>>(dst, counts);
    scan_chunks<<<NB_SCAN, 256, 0, stream>>>(counts, ro, bsums, NNODE);
    scan_bsums<<<1, 256, 0, stream>>>(bsums, NB_SCAN);
    scan_add<<<NB_N, 256, 0, stream>>>(ro, bsums, NNODE);
    scatter_edges<<<NB_E, 256, 0, stream>>>(dst, ro, cursor, eidx);

    for (int l = 0; l < 3; l++) {
        const float* nf_cur = (l == 0) ? nf : nfA;
        const float* ef_cur = (l == 0) ? ef : efA;
        float* nf_next = (l == 2) ? out : nfA;
        node_gemm<<<NB_N, 256, 0, stream>>>(nf_cur, Wni + l * 4096, Wnj + l * 4096,
                                            Wnd + l * 4096, fni, fnj, hmat);
        if (l < 2)
            edge_kernel<true><<<NB_E, 256, 0, stream>>>(ef_cur, src, dst, fni, fnj,
                                                        Wfij + l * 4096, attn + l * 128,
                                                        bias + l * 128, logits, efA);
        else
            edge_kernel<false><<<NB_E, 256, 0, stream>>>(ef_cur, src, dst, fni, fnj,
                                                         Wfij + l * 4096, attn + l * 128,
                                                         bias + l * 128, logits, nullptr);
        aggregate<<<NB_AGG, 256, 0, stream>>>(ro, eidx, src, logits, hmat, nf_next);
    }
}

// Round 2
// 2891.288 us; speedup vs baseline: 1.0052x; 1.0052x over previous
//
#include <hip/hip_runtime.h>

#define NNODE 100000
#define NEDGE 800000
// H = 4, D = 32, H*D = 128, DN = DE = 32, NL = 3

// ---------------------------------------------------------------------------
// CSR build kernels (dst-indexed), run once per call
// ---------------------------------------------------------------------------
__global__ __launch_bounds__(256) void zero_ints(int* __restrict__ a, int* __restrict__ b, int n) {
    int i = blockIdx.x * 256 + threadIdx.x;
    if (i < n) { a[i] = 0; b[i] = 0; }
}

__global__ __launch_bounds__(256) void count_dst(const int* __restrict__ dst, int* __restrict__ counts) {
    int e = blockIdx.x * 256 + threadIdx.x;
    if (e < NEDGE) atomicAdd(&counts[dst[e]], 1);
}

// chunk = 1024 elements per block (256 thr x 4)
__global__ __launch_bounds__(256) void scan_chunks(const int* __restrict__ counts, int* __restrict__ ro,
                                                   int* __restrict__ bsums, int n) {
    __shared__ int sh[256];
    int base = blockIdx.x * 1024;
    int t = threadIdx.x;
    int v[4];
    int s = 0;
    #pragma unroll
    for (int i = 0; i < 4; i++) {
        int idx = base + t * 4 + i;
        int c = (idx < n) ? counts[idx] : 0;
        v[i] = s; s += c;
    }
    sh[t] = s; __syncthreads();
    for (int off = 1; off < 256; off <<= 1) {
        int x = 0;
        if (t >= off) x = sh[t - off];
        __syncthreads();
        if (t >= off) sh[t] += x;
        __syncthreads();
    }
    int thr_excl = (t > 0) ? sh[t - 1] : 0;
    #pragma unroll
    for (int i = 0; i < 4; i++) {
        int idx = base + t * 4 + i;
        if (idx < n) ro[idx] = thr_excl + v[i];
    }
    if (t == 255) bsums[blockIdx.x] = sh[255];
}

__global__ __launch_bounds__(256) void scan_bsums(int* __restrict__ bsums, int nb) {
    __shared__ int sh[256];
    int t = threadIdx.x;
    int val = (t < nb) ? bsums[t] : 0;
    sh[t] = val; __syncthreads();
    for (int off = 1; off < 256; off <<= 1) {
        int x = 0;
        if (t >= off) x = sh[t - off];
        __syncthreads();
        if (t >= off) sh[t] += x;
        __syncthreads();
    }
    int excl = (t > 0) ? sh[t - 1] : 0;
    if (t < nb) bsums[t] = excl;
}

__global__ __launch_bounds__(256) void scan_add(int* __restrict__ ro, const int* __restrict__ bsums, int n) {
    int i = blockIdx.x * 256 + threadIdx.x;
    if (i < n) ro[i] += bsums[i >> 10];
    if (i == 0) ro[n] = NEDGE;
}

// also emits src/dst in dst-sorted edge order
__global__ __launch_bounds__(256) void scatter_edges(const int* __restrict__ src, const int* __restrict__ dst,
                                                     const int* __restrict__ ro, int* __restrict__ cursor,
                                                     int* __restrict__ eidx, int* __restrict__ src_p,
                                                     int* __restrict__ dst_p) {
    int e = blockIdx.x * 256 + threadIdx.x;
    if (e < NEDGE) {
        int d = dst[e];
        int pos = atomicAdd(&cursor[d], 1);
        int idx = ro[d] + pos;
        eidx[idx] = e;
        src_p[idx] = src[e];
        dst_p[idx] = d;
    }
}

// ---------------------------------------------------------------------------
// Layer kernels
// ---------------------------------------------------------------------------

// layer-0 only: f_nj = nf @ Wnj (one thread per node)
__global__ __launch_bounds__(256) void fnj0_kernel(
    const float* __restrict__ nf, const float* __restrict__ Wnj, float* __restrict__ f_nj) {
    int n = blockIdx.x * 256 + threadIdx.x;
    if (n >= NNODE) return;
    float nv[32];
    const float4* nr = (const float4*)(nf + (size_t)n * 32);
    #pragma unroll
    for (int i = 0; i < 8; i++) {
        float4 q = nr[i];
        nv[4 * i] = q.x; nv[4 * i + 1] = q.y; nv[4 * i + 2] = q.z; nv[4 * i + 3] = q.w;
    }
    float* O = f_nj + (size_t)n * 128;
    for (int h = 0; h < 4; h++) {
        float acc[32];
        #pragma unroll
        for (int j = 0; j < 32; j++) acc[j] = 0.f;
        #pragma unroll
        for (int k = 0; k < 32; k++) {
            float v = nv[k];
            #pragma unroll
            for (int j = 0; j < 32; j++)
                acc[j] = fmaf(v, Wnj[k * 128 + h * 32 + j], acc[j]);
        }
        #pragma unroll
        for (int j0 = 0; j0 < 8; j0++)
            *(float4*)(O + h * 32 + 4 * j0) =
                make_float4(acc[4 * j0], acc[4 * j0 + 1], acc[4 * j0 + 2], acc[4 * j0 + 3]);
    }
}

// Per (permuted) edge: f_ni on the fly from nf[src]; f_fij = ef@Wf;
// x = leaky(f_ni + f_nj[dst] + f_fij + bias); logits = <x, attn>; ef_out = mean_h x
template <bool WRITE_EF, bool GATHER_EF>
__global__ __launch_bounds__(256) void edge_kernel(
    const float* __restrict__ ef_in,     // E x 32 (orig order if GATHER_EF else permuted)
    const int* __restrict__ eidx,        // permuted -> orig (GATHER_EF only)
    const int* __restrict__ src_p, const int* __restrict__ dst_p,
    const float* __restrict__ nf_cur,    // N x 32
    const float* __restrict__ f_nj,      // N x 128
    const float* __restrict__ Wni,       // 32x128 layer slice
    const float* __restrict__ Wf,        // 32x128 layer slice
    const float* __restrict__ attn,      // 4x32 layer slice
    const float* __restrict__ bias,      // 128 layer slice
    float* __restrict__ logits,          // E x 4 (permuted order)
    float* __restrict__ ef_out) {        // E x 32 (permuted order)
    int e = blockIdx.x * 256 + threadIdx.x;
    if (e >= NEDGE) return;
    int esrc_row = GATHER_EF ? eidx[e] : e;
    float efv[32];
    const float4* er = (const float4*)(ef_in + (size_t)esrc_row * 32);
    #pragma unroll
    for (int i = 0; i < 8; i++) {
        float4 q = er[i];
        efv[4 * i] = q.x; efv[4 * i + 1] = q.y; efv[4 * i + 2] = q.z; efv[4 * i + 3] = q.w;
    }
    int s = src_p[e], d = dst_p[e];
    float nfs[32];
    const float4* sr = (const float4*)(nf_cur + (size_t)s * 32);
    #pragma unroll
    for (int i = 0; i < 8; i++) {
        float4 q = sr[i];
        nfs[4 * i] = q.x; nfs[4 * i + 1] = q.y; nfs[4 * i + 2] = q.z; nfs[4 * i + 3] = q.w;
    }
    const float* njr = f_nj + (size_t)d * 128;
    float macc[32];
    #pragma unroll
    for (int j = 0; j < 32; j++) macc[j] = 0.f;
    float lg[4];
    #pragma unroll
    for (int h = 0; h < 4; h++) {
        float acc[32];
        #pragma unroll
        for (int j = 0; j < 32; j++) acc[j] = bias[h * 32 + j];
        #pragma unroll
        for (int k = 0; k < 32; k++) {
            float v = efv[k];
            #pragma unroll
            for (int j = 0; j < 32; j++)
                acc[j] = fmaf(v, Wf[k * 128 + h * 32 + j], acc[j]);
        }
        #pragma unroll
        for (int k = 0; k < 32; k++) {
            float v = nfs[k];
            #pragma unroll
            for (int j = 0; j < 32; j++)
                acc[j] = fmaf(v, Wni[k * 128 + h * 32 + j], acc[j]);
        }
        float lgh = 0.f;
        #pragma unroll
        for (int j0 = 0; j0 < 8; j0++) {
            float4 b = *(const float4*)(njr + h * 32 + 4 * j0);
            float bv[4] = {b.x, b.y, b.z, b.w};
            #pragma unroll
            for (int q = 0; q < 4; q++) {
                int j = 4 * j0 + q;
                float x = acc[j] + bv[q];
                x = (x >= 0.f) ? x : 0.2f * x;
                lgh = fmaf(x, attn[h * 32 + j], lgh);
                macc[j] += x;
            }
        }
        lg[h] = lgh;
    }
    *(float4*)(logits + (size_t)e * 4) = make_float4(lg[0], lg[1], lg[2], lg[3]);
    if (WRITE_EF) {
        float4* eo = (float4*)(ef_out + (size_t)e * 32);
        #pragma unroll
        for (int i = 0; i < 8; i++)
            eo[i] = make_float4(macc[4 * i] * 0.25f, macc[4 * i + 1] * 0.25f,
                                macc[4 * i + 2] * 0.25f, macc[4 * i + 3] * 0.25f);
    }
}

// One wave per dst node; contiguous edge range [ro[v], ro[v+1]).
// Lane l accumulates agg cols l (head l>>5) and l+64 (head 2+(l>>5)), k = l&31.
// agg[v][h*32+k] = sum_e softmax_a(e,h) * nf[src_e][k]
__global__ __launch_bounds__(256) void aggregate(
    const int* __restrict__ ro, const int* __restrict__ src_p,
    const float* __restrict__ logits,  // E x 4 (permuted)
    const float* __restrict__ nf_cur,  // N x 32
    float* __restrict__ agg) {         // N x 128
    int wid = (blockIdx.x * 256 + threadIdx.x) >> 6;
    int lane = threadIdx.x & 63;
    if (wid >= NNODE) return;
    int beg = ro[wid], end = ro[wid + 1];
    float* arow = agg + (size_t)wid * 128;
    if (beg == end) {
        arow[lane] = 0.f;
        arow[lane + 64] = 0.f;
        return;
    }
    int hA = lane >> 5;
    int k = lane & 31;
    float m1 = -1e30f, m2 = -1e30f;
    for (int i = beg; i < end; i++) {
        m1 = fmaxf(m1, logits[(size_t)i * 4 + hA]);
        m2 = fmaxf(m2, logits[(size_t)i * 4 + hA + 2]);
    }
    float den1 = 0.f, den2 = 0.f, acc1 = 0.f, acc2 = 0.f;
    for (int i = beg; i < end; i++) {
        int s = src_p[i];
        float a1 = __expf(logits[(size_t)i * 4 + hA] - m1);
        float a2 = __expf(logits[(size_t)i * 4 + hA + 2] - m2);
        den1 += a1; den2 += a2;
        float v = nf_cur[(size_t)s * 32 + k];
        acc1 = fmaf(a1, v, acc1);
        acc2 = fmaf(a2, v, acc2);
    }
    arow[lane] = acc1 / den1;
    arow[lane + 64] = acc2 / den2;
}

// Per node: h_out mean over heads via Wnode; optionally also next layer's f_nj.
template <bool WRITE_FNJ>
__global__ __launch_bounds__(256) void post_kernel(
    const float* __restrict__ agg,        // N x 128
    const float* __restrict__ Wnode,      // 32x128 layer slice
    const float* __restrict__ Wnj_next,   // 32x128 next-layer slice (if WRITE_FNJ)
    float* __restrict__ nf_next,          // N x 32
    float* __restrict__ fnj_next) {       // N x 128 (if WRITE_FNJ)
    int n = blockIdx.x * 256 + threadIdx.x;
    if (n >= NNODE) return;
    float acc[32];
    #pragma unroll
    for (int d = 0; d < 32; d++) acc[d] = 0.f;
    const float* ar = agg + (size_t)n * 128;
    for (int h = 0; h < 4; h++) {
        float av[32];
        #pragma unroll
        for (int i = 0; i < 8; i++) {
            float4 q = *(const float4*)(ar + h * 32 + 4 * i);
            av[4 * i] = q.x; av[4 * i + 1] = q.y; av[4 * i + 2] = q.z; av[4 * i + 3] = q.w;
        }
        #pragma unroll
        for (int kk = 0; kk < 32; kk++) {
            float v = av[kk];
            #pragma unroll
            for (int d = 0; d < 32; d++)
                acc[d] = fmaf(v, Wnode[kk * 128 + h * 32 + d], acc[d]);
        }
    }
    #pragma unroll
    for (int d = 0; d < 32; d++) acc[d] *= 0.25f;
    float* orow = nf_next + (size_t)n * 32;
    #pragma unroll
    for (int d0 = 0; d0 < 8; d0++)
        *(float4*)(orow + 4 * d0) =
            make_float4(acc[4 * d0], acc[4 * d0 + 1], acc[4 * d0 + 2], acc[4 * d0 + 3]);
    if (WRITE_FNJ) {
        float* frow = fnj_next + (size_t)n * 128;
        for (int h = 0; h < 4; h++) {
            float a2[32];
            #pragma unroll
            for (int j = 0; j < 32; j++) a2[j] = 0.f;
            #pragma unroll
            for (int d = 0; d < 32; d++) {
                float v = acc[d];
                #pragma unroll
                for (int j = 0; j < 32; j++)
                    a2[j] = fmaf(v, Wnj_next[d * 128 + h * 32 + j], a2[j]);
            }
            #pragma unroll
            for (int j0 = 0; j0 < 8; j0++)
                *(float4*)(frow + h * 32 + 4 * j0) =
                    make_float4(a2[4 * j0], a2[4 * j0 + 1], a2[4 * j0 + 2], a2[4 * j0 + 3]);
        }
    }
}

// ---------------------------------------------------------------------------
extern "C" void kernel_launch(void* const* d_in, const int* in_sizes, int n_in,
                              void* d_out, int out_size, void* d_ws, size_t ws_size,
                              hipStream_t stream) {
    const float* nf   = (const float*)d_in[0];
    const float* ef   = (const float*)d_in[1];
    const int*   src  = (const int*)d_in[2];
    const int*   dst  = (const int*)d_in[3];
    const float* Wni  = (const float*)d_in[4];
    const float* Wnj  = (const float*)d_in[5];
    const float* Wfij = (const float*)d_in[6];
    const float* Wnd  = (const float*)d_in[7];
    const float* attn = (const float*)d_in[8];
    const float* bias = (const float*)d_in[9];
    float* out = (float*)d_out;

    char* ws = (char*)d_ws;
    size_t off = 0;
    auto alloc = [&](size_t bytes) {
        void* p = ws + off;
        off += (bytes + 255) & ~(size_t)255;
        return p;
    };
    float* fnj    = (float*)alloc((size_t)NNODE * 128 * 4);
    float* agg    = (float*)alloc((size_t)NNODE * 128 * 4);
    float* efA    = (float*)alloc((size_t)NEDGE * 32 * 4);
    float* logits = (float*)alloc((size_t)NEDGE * 4 * 4);
    float* nfA    = (float*)alloc((size_t)NNODE * 32 * 4);
    float* nfB    = (float*)alloc((size_t)NNODE * 32 * 4);
    int*   counts = (int*)alloc((size_t)NNODE * 4);
    int*   cursor = (int*)alloc((size_t)NNODE * 4);
    int*   ro     = (int*)alloc((size_t)(NNODE + 1) * 4);
    int*   eidx   = (int*)alloc((size_t)NEDGE * 4);
    int*   src_p  = (int*)alloc((size_t)NEDGE * 4);
    int*   dst_p  = (int*)alloc((size_t)NEDGE * 4);
    int*   bsums  = (int*)alloc(1024 * 4);

    const int NB_E = (NEDGE + 255) / 256;          // 3125
    const int NB_N = (NNODE + 255) / 256;          // 391
    const int NB_AGG = (NNODE + 3) / 4;            // 25000 (4 waves/block)
    const int NB_SCAN = (NNODE + 1023) / 1024;     // 98

    // Build dst-sorted CSR + permuted edge arrays (once per call)
    zero_ints<<<NB_N, 256, 0, stream>>>(counts, cursor, NNODE);
    count_dst<<<NB_E, 256, 0, stream>>>(dst, counts);
    scan_chunks<<<NB_SCAN, 256, 0, stream>>>(counts, ro, bsums, NNODE);
    scan_bsums<<<1, 256, 0, stream>>>(bsums, NB_SCAN);
    scan_add<<<NB_N, 256, 0, stream>>>(ro, bsums, NNODE);
    scatter_edges<<<NB_E, 256, 0, stream>>>(src, dst, ro, cursor, eidx, src_p, dst_p);

    // layer 0 f_nj from input nf
    fnj0_kernel<<<NB_N, 256, 0, stream>>>(nf, Wnj, fnj);

    // ----- layer 0 -----
    edge_kernel<true, true><<<NB_E, 256, 0, stream>>>(ef, eidx, src_p, dst_p, nf, fnj,
                                                      Wni, Wfij, attn, bias, logits, efA);
    aggregate<<<NB_AGG, 256, 0, stream>>>(ro, src_p, logits, nf, agg);
    post_kernel<true><<<NB_N, 256, 0, stream>>>(agg, Wnd, Wnj + 4096, nfA, fnj);

    // ----- layer 1 -----
    edge_kernel<true, false><<<NB_E, 256, 0, stream>>>(efA, nullptr, src_p, dst_p, nfA, fnj,
                                                       Wni + 4096, Wfij + 4096, attn + 128,
                                                       bias + 128, logits, efA);
    aggregate<<<NB_AGG, 256, 0, stream>>>(ro, src_p, logits, nfA, agg);
    post_kernel<true><<<NB_N, 256, 0, stream>>>(agg, Wnd + 4096, Wnj + 8192, nfB, fnj);

    // ----- layer 2 -----
    edge_kernel<false, false><<<NB_E, 256, 0, stream>>>(efA, nullptr, src_p, dst_p, nfB, fnj,
                                                        Wni + 8192, Wfij + 8192, attn + 256,
                                                        bias + 256, logits, nullptr);
    aggregate<<<NB_AGG, 256, 0, stream>>>(ro, src_p, logits, nfB, agg);
    post_kernel<false><<<NB_N, 256, 0, stream>>>(agg, Wnd + 8192, nullptr, out, nullptr);
}

// Round 3
// 1237.508 us; speedup vs baseline: 2.3484x; 2.3364x over previous
//
#include <hip/hip_runtime.h>

#define NNODE 100000
#define NEDGE 800000
#define EB 128
// H = 4, D = 32, H*D = 128, DN = DE = 32, NL = 3

// ---------------------------------------------------------------------------
// CSR build kernels (dst-indexed), run once per call
// ---------------------------------------------------------------------------
__global__ __launch_bounds__(256) void zero_ints(int* __restrict__ a, int* __restrict__ b, int n) {
    int i = blockIdx.x * 256 + threadIdx.x;
    if (i < n) { a[i] = 0; b[i] = 0; }
}

__global__ __launch_bounds__(256) void count_dst(const int* __restrict__ dst, int* __restrict__ counts) {
    int e = blockIdx.x * 256 + threadIdx.x;
    if (e < NEDGE) atomicAdd(&counts[dst[e]], 1);
}

__global__ __launch_bounds__(256) void scan_chunks(const int* __restrict__ counts, int* __restrict__ ro,
                                                   int* __restrict__ bsums, int n) {
    __shared__ int sh[256];
    int base = blockIdx.x * 1024;
    int t = threadIdx.x;
    int v[4];
    int s = 0;
    #pragma unroll
    for (int i = 0; i < 4; i++) {
        int idx = base + t * 4 + i;
        int c = (idx < n) ? counts[idx] : 0;
        v[i] = s; s += c;
    }
    sh[t] = s; __syncthreads();
    for (int off = 1; off < 256; off <<= 1) {
        int x = 0;
        if (t >= off) x = sh[t - off];
        __syncthreads();
        if (t >= off) sh[t] += x;
        __syncthreads();
    }
    int thr_excl = (t > 0) ? sh[t - 1] : 0;
    #pragma unroll
    for (int i = 0; i < 4; i++) {
        int idx = base + t * 4 + i;
        if (idx < n) ro[idx] = thr_excl + v[i];
    }
    if (t == 255) bsums[blockIdx.x] = sh[255];
}

__global__ __launch_bounds__(256) void scan_bsums(int* __restrict__ bsums, int nb) {
    __shared__ int sh[256];
    int t = threadIdx.x;
    int val = (t < nb) ? bsums[t] : 0;
    sh[t] = val; __syncthreads();
    for (int off = 1; off < 256; off <<= 1) {
        int x = 0;
        if (t >= off) x = sh[t - off];
        __syncthreads();
        if (t >= off) sh[t] += x;
        __syncthreads();
    }
    int excl = (t > 0) ? sh[t - 1] : 0;
    if (t < nb) bsums[t] = excl;
}

__global__ __launch_bounds__(256) void scan_add(int* __restrict__ ro, const int* __restrict__ bsums, int n) {
    int i = blockIdx.x * 256 + threadIdx.x;
    if (i < n) ro[i] += bsums[i >> 10];
    if (i == 0) ro[n] = NEDGE;
}

__global__ __launch_bounds__(256) void scatter_edges(const int* __restrict__ src, const int* __restrict__ dst,
                                                     const int* __restrict__ ro, int* __restrict__ cursor,
                                                     int* __restrict__ eidx, int* __restrict__ src_p,
                                                     int* __restrict__ dst_p) {
    int e = blockIdx.x * 256 + threadIdx.x;
    if (e < NEDGE) {
        int d = dst[e];
        int pos = atomicAdd(&cursor[d], 1);
        int idx = ro[d] + pos;
        eidx[idx] = e;
        src_p[idx] = src[e];
        dst_p[idx] = d;
    }
}

// ---------------------------------------------------------------------------
// Node-side kernels (unchanged structure)
// ---------------------------------------------------------------------------

// f_nj = nf @ Wnj (one thread per node)
__global__ __launch_bounds__(256) void fnj0_kernel(
    const float* __restrict__ nf, const float* __restrict__ Wnj, float* __restrict__ f_nj) {
    int n = blockIdx.x * 256 + threadIdx.x;
    if (n >= NNODE) return;
    float nv[32];
    const float4* nr = (const float4*)(nf + (size_t)n * 32);
    #pragma unroll
    for (int i = 0; i < 8; i++) {
        float4 q = nr[i];
        nv[4 * i] = q.x; nv[4 * i + 1] = q.y; nv[4 * i + 2] = q.z; nv[4 * i + 3] = q.w;
    }
    float* O = f_nj + (size_t)n * 128;
    for (int h = 0; h < 4; h++) {
        float acc[32];
        #pragma unroll
        for (int j = 0; j < 32; j++) acc[j] = 0.f;
        #pragma unroll
        for (int k = 0; k < 32; k++) {
            float v = nv[k];
            #pragma unroll
            for (int j = 0; j < 32; j++)
                acc[j] = fmaf(v, Wnj[k * 128 + h * 32 + j], acc[j]);
        }
        #pragma unroll
        for (int j0 = 0; j0 < 8; j0++)
            *(float4*)(O + h * 32 + 4 * j0) =
                make_float4(acc[4 * j0], acc[4 * j0 + 1], acc[4 * j0 + 2], acc[4 * j0 + 3]);
    }
}

// ---------------------------------------------------------------------------
// Tiled edge kernel: C[e][j] = sum_k A[e][k]*W[k][j], A = [ef | nf[src]], K=64
// Block: 128 edges x 128 j, 256 threads, 8x8 register tile.
// ---------------------------------------------------------------------------
template <bool WRITE_EF, bool GATHER_EF>
__global__ __launch_bounds__(256) void edge_tile_kernel(
    const float* __restrict__ ef_in,     // E x 32 (orig order if GATHER_EF else permuted)
    const int* __restrict__ eidx,        // permuted -> orig (GATHER_EF only)
    const int* __restrict__ src_p, const int* __restrict__ dst_p,
    const float* __restrict__ nf_cur,    // N x 32
    const float* __restrict__ f_nj,      // N x 128
    const float* __restrict__ Wni,       // 32x128 layer slice
    const float* __restrict__ Wf,        // 32x128 layer slice
    const float* __restrict__ attn,      // 4x32 layer slice
    const float* __restrict__ bias,      // 128 layer slice
    float* __restrict__ logits,          // E x 4 (permuted order)
    float* __restrict__ ef_out) {        // E x 32 (permuted order)
    __shared__ float sA[64 * 128];       // A_T[k][e]; k<32: ef, k>=32: nf[src]
    __shared__ float sW[64 * 144];       // W[k][j] skewed: elem j at j + 4*(j>>5)

    int t = threadIdx.x;
    int e0b = blockIdx.x * EB;

    // ---- stage W: rows 0..31 = Wf, rows 32..63 = Wni ----
    {
        const float4* wf4 = (const float4*)Wf;
        const float4* wn4 = (const float4*)Wni;
        #pragma unroll
        for (int i = 0; i < 4; i++) {
            int f = t + i * 256;             // float4 index 0..1023
            int k = f >> 5, jq = f & 31;     // j = jq*4
            int dstoff = k * 144 + jq * 4 + 4 * (jq >> 3);
            *(float4*)(sW + dstoff) = wf4[f];
            *(float4*)(sW + (32 * 144) + dstoff) = wn4[f];
        }
    }

    // ---- stage A (transposed) ----
    {
        int e = t & 127;
        int c0 = (t >> 7) * 4;   // 0 or 4
        long erow;
        if (GATHER_EF) erow = eidx[e0b + e]; else erow = e0b + e;
        const float4* er = (const float4*)(ef_in + (size_t)erow * 32);
        int s = src_p[e0b + e];
        const float4* srow = (const float4*)(nf_cur + (size_t)s * 32);
        #pragma unroll
        for (int i = 0; i < 4; i++) {
            int c = c0 + i;                 // 0..7
            float4 v = er[c];
            sA[(c * 4 + 0) * 128 + e] = v.x;
            sA[(c * 4 + 1) * 128 + e] = v.y;
            sA[(c * 4 + 2) * 128 + e] = v.z;
            sA[(c * 4 + 3) * 128 + e] = v.w;
        }
        #pragma unroll
        for (int i = 0; i < 4; i++) {
            int c = c0 + i;
            float4 v = srow[c];
            sA[(32 + c * 4 + 0) * 128 + e] = v.x;
            sA[(32 + c * 4 + 1) * 128 + e] = v.y;
            sA[(32 + c * 4 + 2) * 128 + e] = v.z;
            sA[(32 + c * 4 + 3) * 128 + e] = v.w;
        }
    }
    __syncthreads();

    int jg = t & 15, eg = t >> 4;
    int j0 = jg * 8, e0 = eg * 8;
    int woff = jg * 8 + 4 * (jg >> 2);   // skewed base for this thread's 8 j's

    // acc init = bias[j]
    float bj[8];
    {
        float4 b0 = *(const float4*)(bias + j0);
        float4 b1 = *(const float4*)(bias + j0 + 4);
        bj[0] = b0.x; bj[1] = b0.y; bj[2] = b0.z; bj[3] = b0.w;
        bj[4] = b1.x; bj[5] = b1.y; bj[6] = b1.z; bj[7] = b1.w;
    }
    float acc[8][8];
    #pragma unroll
    for (int i = 0; i < 8; i++)
        #pragma unroll
        for (int j = 0; j < 8; j++) acc[i][j] = bj[j];

    #pragma unroll 4
    for (int k = 0; k < 64; k++) {
        float4 a0 = *(const float4*)(sA + k * 128 + e0);
        float4 a1 = *(const float4*)(sA + k * 128 + e0 + 4);
        float4 w0 = *(const float4*)(sW + k * 144 + woff);
        float4 w1 = *(const float4*)(sW + k * 144 + woff + 4);
        float av[8] = {a0.x, a0.y, a0.z, a0.w, a1.x, a1.y, a1.z, a1.w};
        float wv[8] = {w0.x, w0.y, w0.z, w0.w, w1.x, w1.y, w1.z, w1.w};
        #pragma unroll
        for (int i = 0; i < 8; i++)
            #pragma unroll
            for (int j = 0; j < 8; j++)
                acc[i][j] = fmaf(av[i], wv[j], acc[i][j]);
    }

    // ---- epilogue ----
    int h = jg >> 2;
    float atv[8];
    {
        const float* ap = attn + h * 32 + (jg & 3) * 8;
        float4 a0 = *(const float4*)(ap);
        float4 a1 = *(const float4*)(ap + 4);
        atv[0] = a0.x; atv[1] = a0.y; atv[2] = a0.z; atv[3] = a0.w;
        atv[4] = a1.x; atv[5] = a1.y; atv[6] = a1.z; atv[7] = a1.w;
    }
    float lg[8];
    #pragma unroll
    for (int i = 0; i < 8; i++) {
        int d = dst_p[e0b + e0 + i];
        const float* fr = f_nj + (size_t)d * 128 + j0;
        float4 f0 = *(const float4*)(fr);
        float4 f1 = *(const float4*)(fr + 4);
        float fv[8] = {f0.x, f0.y, f0.z, f0.w, f1.x, f1.y, f1.z, f1.w};
        float x[8];
        float lgh = 0.f;
        #pragma unroll
        for (int j = 0; j < 8; j++) {
            float v = acc[i][j] + fv[j];
            v = (v >= 0.f) ? v : 0.2f * v;
            x[j] = v;
            lgh = fmaf(v, atv[j], lgh);
        }
        lg[i] = lgh;
        if (WRITE_EF) {
            // mean over heads: j and j^32, j^64 live at lanes jg^4, jg^8
            #pragma unroll
            for (int j = 0; j < 8; j++) {
                x[j] += __shfl_xor(x[j], 4);
                x[j] += __shfl_xor(x[j], 8);
            }
            if (jg < 4) {
                float* eo = ef_out + (size_t)(e0b + e0 + i) * 32 + jg * 8;
                *(float4*)(eo) = make_float4(x[0] * 0.25f, x[1] * 0.25f, x[2] * 0.25f, x[3] * 0.25f);
                *(float4*)(eo + 4) = make_float4(x[4] * 0.25f, x[5] * 0.25f, x[6] * 0.25f, x[7] * 0.25f);
            }
        }
    }
    // logits: reduce over the 4 jg's of the same head
    #pragma unroll
    for (int i = 0; i < 8; i++) {
        lg[i] += __shfl_xor(lg[i], 1);
        lg[i] += __shfl_xor(lg[i], 2);
    }
    if ((jg & 3) == 0) {
        #pragma unroll
        for (int i = 0; i < 8; i++)
            logits[(size_t)(e0b + e0 + i) * 4 + h] = lg[i];
    }
}

// ---------------------------------------------------------------------------
// One wave per dst node; contiguous edge range [ro[v], ro[v+1]).
__global__ __launch_bounds__(256) void aggregate(
    const int* __restrict__ ro, const int* __restrict__ src_p,
    const float* __restrict__ logits,  // E x 4 (permuted)
    const float* __restrict__ nf_cur,  // N x 32
    float* __restrict__ agg) {         // N x 128
    int wid = (blockIdx.x * 256 + threadIdx.x) >> 6;
    int lane = threadIdx.x & 63;
    if (wid >= NNODE) return;
    int beg = ro[wid], end = ro[wid + 1];
    float* arow = agg + (size_t)wid * 128;
    if (beg == end) {
        arow[lane] = 0.f;
        arow[lane + 64] = 0.f;
        return;
    }
    int hA = lane >> 5;
    int k = lane & 31;
    float m1 = -1e30f, m2 = -1e30f;
    for (int i = beg; i < end; i++) {
        m1 = fmaxf(m1, logits[(size_t)i * 4 + hA]);
        m2 = fmaxf(m2, logits[(size_t)i * 4 + hA + 2]);
    }
    float den1 = 0.f, den2 = 0.f, acc1 = 0.f, acc2 = 0.f;
    for (int i = beg; i < end; i++) {
        int s = src_p[i];
        float a1 = __expf(logits[(size_t)i * 4 + hA] - m1);
        float a2 = __expf(logits[(size_t)i * 4 + hA + 2] - m2);
        den1 += a1; den2 += a2;
        float v = nf_cur[(size_t)s * 32 + k];
        acc1 = fmaf(a1, v, acc1);
        acc2 = fmaf(a2, v, acc2);
    }
    arow[lane] = acc1 / den1;
    arow[lane + 64] = acc2 / den2;
}

// Per node: h_out mean over heads via Wnode; optionally also next layer's f_nj.
template <bool WRITE_FNJ>
__global__ __launch_bounds__(256) void post_kernel(
    const float* __restrict__ agg,        // N x 128
    const float* __restrict__ Wnode,      // 32x128 layer slice
    const float* __restrict__ Wnj_next,   // 32x128 next-layer slice (if WRITE_FNJ)
    float* __restrict__ nf_next,          // N x 32
    float* __restrict__ fnj_next) {       // N x 128 (if WRITE_FNJ)
    int n = blockIdx.x * 256 + threadIdx.x;
    if (n >= NNODE) return;
    float acc[32];
    #pragma unroll
    for (int d = 0; d < 32; d++) acc[d] = 0.f;
    const float* ar = agg + (size_t)n * 128;
    for (int h = 0; h < 4; h++) {
        float av[32];
        #pragma unroll
        for (int i = 0; i < 8; i++) {
            float4 q = *(const float4*)(ar + h * 32 + 4 * i);
            av[4 * i] = q.x; av[4 * i + 1] = q.y; av[4 * i + 2] = q.z; av[4 * i + 3] = q.w;
        }
        #pragma unroll
        for (int kk = 0; kk < 32; kk++) {
            float v = av[kk];
            #pragma unroll
            for (int d = 0; d < 32; d++)
                acc[d] = fmaf(v, Wnode[kk * 128 + h * 32 + d], acc[d]);
        }
    }
    #pragma unroll
    for (int d = 0; d < 32; d++) acc[d] *= 0.25f;
    float* orow = nf_next + (size_t)n * 32;
    #pragma unroll
    for (int d0 = 0; d0 < 8; d0++)
        *(float4*)(orow + 4 * d0) =
            make_float4(acc[4 * d0], acc[4 * d0 + 1], acc[4 * d0 + 2], acc[4 * d0 + 3]);
    if (WRITE_FNJ) {
        float* frow = fnj_next + (size_t)n * 128;
        for (int h = 0; h < 4; h++) {
            float a2[32];
            #pragma unroll
            for (int j = 0; j < 32; j++) a2[j] = 0.f;
            #pragma unroll
            for (int d = 0; d < 32; d++) {
                float v = acc[d];
                #pragma unroll
                for (int j = 0; j < 32; j++)
                    a2[j] = fmaf(v, Wnj_next[d * 128 + h * 32 + j], a2[j]);
            }
            #pragma unroll
            for (int j0 = 0; j0 < 8; j0++)
                *(float4*)(frow + h * 32 + 4 * j0) =
                    make_float4(a2[4 * j0], a2[4 * j0 + 1], a2[4 * j0 + 2], a2[4 * j0 + 3]);
        }
    }
}

// ---------------------------------------------------------------------------
extern "C" void kernel_launch(void* const* d_in, const int* in_sizes, int n_in,
                              void* d_out, int out_size, void* d_ws, size_t ws_size,
                              hipStream_t stream) {
    const float* nf   = (const float*)d_in[0];
    const float* ef   = (const float*)d_in[1];
    const int*   src  = (const int*)d_in[2];
    const int*   dst  = (const int*)d_in[3];
    const float* Wni  = (const float*)d_in[4];
    const float* Wnj  = (const float*)d_in[5];
    const float* Wfij = (const float*)d_in[6];
    const float* Wnd  = (const float*)d_in[7];
    const float* attn = (const float*)d_in[8];
    const float* bias = (const float*)d_in[9];
    float* out = (float*)d_out;

    char* ws = (char*)d_ws;
    size_t off = 0;
    auto alloc = [&](size_t bytes) {
        void* p = ws + off;
        off += (bytes + 255) & ~(size_t)255;
        return p;
    };
    float* fnj    = (float*)alloc((size_t)NNODE * 128 * 4);
    float* agg    = (float*)alloc((size_t)NNODE * 128 * 4);
    float* efA    = (float*)alloc((size_t)NEDGE * 32 * 4);
    float* logits = (float*)alloc((size_t)NEDGE * 4 * 4);
    float* nfA    = (float*)alloc((size_t)NNODE * 32 * 4);
    float* nfB    = (float*)alloc((size_t)NNODE * 32 * 4);
    int*   counts = (int*)alloc((size_t)NNODE * 4);
    int*   cursor = (int*)alloc((size_t)NNODE * 4);
    int*   ro     = (int*)alloc((size_t)(NNODE + 1) * 4);
    int*   eidx   = (int*)alloc((size_t)NEDGE * 4);
    int*   src_p  = (int*)alloc((size_t)NEDGE * 4);
    int*   dst_p  = (int*)alloc((size_t)NEDGE * 4);
    int*   bsums  = (int*)alloc(1024 * 4);

    const int NB_E = (NEDGE + 255) / 256;          // 3125
    const int NB_N = (NNODE + 255) / 256;          // 391
    const int NB_AGG = (NNODE + 3) / 4;            // 25000
    const int NB_SCAN = (NNODE + 1023) / 1024;     // 98
    const int NB_ET = NEDGE / EB;                  // 6250

    zero_ints<<<NB_N, 256, 0, stream>>>(counts, cursor, NNODE);
    count_dst<<<NB_E, 256, 0, stream>>>(dst, counts);
    scan_chunks<<<NB_SCAN, 256, 0, stream>>>(counts, ro, bsums, NNODE);
    scan_bsums<<<1, 256, 0, stream>>>(bsums, NB_SCAN);
    scan_add<<<NB_N, 256, 0, stream>>>(ro, bsums, NNODE);
    scatter_edges<<<NB_E, 256, 0, stream>>>(src, dst, ro, cursor, eidx, src_p, dst_p);

    fnj0_kernel<<<NB_N, 256, 0, stream>>>(nf, Wnj, fnj);

    // ----- layer 0 -----
    edge_tile_kernel<true, true><<<NB_ET, 256, 0, stream>>>(ef, eidx, src_p, dst_p, nf, fnj,
                                                            Wni, Wfij, attn, bias, logits, efA);
    aggregate<<<NB_AGG, 256, 0, stream>>>(ro, src_p, logits, nf, agg);
    post_kernel<true><<<NB_N, 256, 0, stream>>>(agg, Wnd, Wnj + 4096, nfA, fnj);

    // ----- layer 1 -----
    edge_tile_kernel<true, false><<<NB_ET, 256, 0, stream>>>(efA, nullptr, src_p, dst_p, nfA, fnj,
                                                             Wni + 4096, Wfij + 4096, attn + 128,
                                                             bias + 128, logits, efA);
    aggregate<<<NB_AGG, 256, 0, stream>>>(ro, src_p, logits, nfA, agg);
    post_kernel<true><<<NB_N, 256, 0, stream>>>(agg, Wnd + 4096, Wnj + 8192, nfB, fnj);

    // ----- layer 2 -----
    edge_tile_kernel<false, false><<<NB_ET, 256, 0, stream>>>(efA, nullptr, src_p, dst_p, nfB, fnj,
                                                              Wni + 8192, Wfij + 8192, attn + 256,
                                                              bias + 256, logits, nullptr);
    aggregate<<<NB_AGG, 256, 0, stream>>>(ro, src_p, logits, nfB, agg);
    post_kernel<false><<<NB_N, 256, 0, stream>>>(agg, Wnd + 8192, nullptr, out, nullptr);
}

// Round 4
// 1143.460 us; speedup vs baseline: 2.5416x; 1.0822x over previous
//
#include <hip/hip_runtime.h>

#define NNODE 100000
#define NEDGE 800000
#define EB 128
#define SWS 140   // skewed W row stride in floats
// H = 4, D = 32, H*D = 128, DN = DE = 32, NL = 3

// ---------------------------------------------------------------------------
// CSR build kernels (dst-indexed), run once per call
// ---------------------------------------------------------------------------
__global__ __launch_bounds__(256) void zero_ints(int* __restrict__ a, int* __restrict__ b, int n) {
    int i = blockIdx.x * 256 + threadIdx.x;
    if (i < n) { a[i] = 0; b[i] = 0; }
}

__global__ __launch_bounds__(256) void count_dst(const int* __restrict__ dst, int* __restrict__ counts) {
    int e = blockIdx.x * 256 + threadIdx.x;
    if (e < NEDGE) atomicAdd(&counts[dst[e]], 1);
}

__global__ __launch_bounds__(256) void scan_chunks(const int* __restrict__ counts, int* __restrict__ ro,
                                                   int* __restrict__ bsums, int n) {
    __shared__ int sh[256];
    int base = blockIdx.x * 1024;
    int t = threadIdx.x;
    int v[4];
    int s = 0;
    #pragma unroll
    for (int i = 0; i < 4; i++) {
        int idx = base + t * 4 + i;
        int c = (idx < n) ? counts[idx] : 0;
        v[i] = s; s += c;
    }
    sh[t] = s; __syncthreads();
    for (int off = 1; off < 256; off <<= 1) {
        int x = 0;
        if (t >= off) x = sh[t - off];
        __syncthreads();
        if (t >= off) sh[t] += x;
        __syncthreads();
    }
    int thr_excl = (t > 0) ? sh[t - 1] : 0;
    #pragma unroll
    for (int i = 0; i < 4; i++) {
        int idx = base + t * 4 + i;
        if (idx < n) ro[idx] = thr_excl + v[i];
    }
    if (t == 255) bsums[blockIdx.x] = sh[255];
}

__global__ __launch_bounds__(256) void scan_bsums(int* __restrict__ bsums, int nb) {
    __shared__ int sh[256];
    int t = threadIdx.x;
    int val = (t < nb) ? bsums[t] : 0;
    sh[t] = val; __syncthreads();
    for (int off = 1; off < 256; off <<= 1) {
        int x = 0;
        if (t >= off) x = sh[t - off];
        __syncthreads();
        if (t >= off) sh[t] += x;
        __syncthreads();
    }
    int excl = (t > 0) ? sh[t - 1] : 0;
    if (t < nb) bsums[t] = excl;
}

__global__ __launch_bounds__(256) void scan_add(int* __restrict__ ro, const int* __restrict__ bsums, int n) {
    int i = blockIdx.x * 256 + threadIdx.x;
    if (i < n) ro[i] += bsums[i >> 10];
    if (i == 0) ro[n] = NEDGE;
}

__global__ __launch_bounds__(256) void scatter_edges(const int* __restrict__ src, const int* __restrict__ dst,
                                                     const int* __restrict__ ro, int* __restrict__ cursor,
                                                     int* __restrict__ eidx, int* __restrict__ src_p,
                                                     int* __restrict__ dst_p) {
    int e = blockIdx.x * 256 + threadIdx.x;
    if (e < NEDGE) {
        int d = dst[e];
        int pos = atomicAdd(&cursor[d], 1);
        int idx = ro[d] + pos;
        eidx[idx] = e;
        src_p[idx] = src[e];
        dst_p[idx] = d;
    }
}

// ---------------------------------------------------------------------------
// Tiled edge kernel: C[e][j] = sum_k A[e][k]*W[k][j], A = [ef | nf[src]], K=64
// Block: 128 edges x 128 j, 256 threads, 8x8 register tile.
// K-split staging: sA holds one 32-k chunk at a time (ef chunk, then nf chunk).
// LDS = 64*140*4 (sW) + 32*128*4 (sA) = 52.2 KB -> 3 blocks/CU.
// ---------------------------------------------------------------------------
template <bool WRITE_EF, bool GATHER_EF>
__global__ __launch_bounds__(256) void edge_tile_kernel(
    const float* __restrict__ ef_in,     // E x 32 (orig order if GATHER_EF else permuted)
    const int* __restrict__ eidx,        // permuted -> orig (GATHER_EF only)
    const int* __restrict__ src_p, const int* __restrict__ dst_p,
    const float* __restrict__ nf_cur,    // N x 32
    const float* __restrict__ f_nj,      // N x 128
    const float* __restrict__ Wni,       // 32x128 layer slice
    const float* __restrict__ Wf,        // 32x128 layer slice
    const float* __restrict__ attn,      // 4x32 layer slice
    const float* __restrict__ bias,      // 128 layer slice
    float* __restrict__ logits,          // E x 4 (permuted order)
    float* __restrict__ ef_out) {        // E x 32 (permuted order)
    __shared__ float sW[64 * SWS];       // rows 0..31 = Wf, 32..63 = Wni (skewed)
    __shared__ float sA[32 * 128];       // A_T chunk [k][e]

    int t = threadIdx.x;
    int e0b = blockIdx.x * EB;

    // ---- stage W (whole K=64, once) ----
    {
        const float4* wf4 = (const float4*)Wf;
        const float4* wn4 = (const float4*)Wni;
        #pragma unroll
        for (int i = 0; i < 4; i++) {
            int f = t + i * 256;             // float4 index 0..1023
            int k = f >> 5, jq = f & 31;     // j = jq*4
            int off = k * SWS + jq * 4 + 4 * (jq >> 3);
            *(float4*)(sW + off) = wf4[f];
            *(float4*)(sW + 32 * SWS + off) = wn4[f];
        }
    }

    // ---- stage A phase 1: ef rows (k 0..31), transposed ----
    int e = t & 127;
    int c0 = (t >> 7) * 4;   // 0 or 4
    int ssrc = src_p[e0b + e];
    {
        long erow = GATHER_EF ? (long)eidx[e0b + e] : (long)(e0b + e);
        const float4* er = (const float4*)(ef_in + (size_t)erow * 32);
        #pragma unroll
        for (int i = 0; i < 4; i++) {
            int c = c0 + i;                 // 0..7
            float4 v = er[c];
            sA[(c * 4 + 0) * 128 + e] = v.x;
            sA[(c * 4 + 1) * 128 + e] = v.y;
            sA[(c * 4 + 2) * 128 + e] = v.z;
            sA[(c * 4 + 3) * 128 + e] = v.w;
        }
    }
    __syncthreads();

    // issue phase-2 global loads early (hidden under phase-1 compute)
    float4 nreg[4];
    {
        const float4* srow = (const float4*)(nf_cur + (size_t)ssrc * 32);
        #pragma unroll
        for (int i = 0; i < 4; i++) nreg[i] = srow[c0 + i];
    }

    int jg = t & 15, eg = t >> 4;
    int j0 = jg * 8, e0 = eg * 8;
    int woff = jg * 8 + 4 * (jg >> 2);   // skewed base for this thread's 8 j's

    float bj[8];
    {
        float4 b0 = *(const float4*)(bias + j0);
        float4 b1 = *(const float4*)(bias + j0 + 4);
        bj[0] = b0.x; bj[1] = b0.y; bj[2] = b0.z; bj[3] = b0.w;
        bj[4] = b1.x; bj[5] = b1.y; bj[6] = b1.z; bj[7] = b1.w;
    }
    float acc[8][8];
    #pragma unroll
    for (int i = 0; i < 8; i++)
        #pragma unroll
        for (int j = 0; j < 8; j++) acc[i][j] = bj[j];

    // ---- compute phase 1: k 0..31 (ef @ Wf) ----
    #pragma unroll 4
    for (int k = 0; k < 32; k++) {
        float4 a0 = *(const float4*)(sA + k * 128 + e0);
        float4 a1 = *(const float4*)(sA + k * 128 + e0 + 4);
        float4 w0 = *(const float4*)(sW + k * SWS + woff);
        float4 w1 = *(const float4*)(sW + k * SWS + woff + 4);
        float av[8] = {a0.x, a0.y, a0.z, a0.w, a1.x, a1.y, a1.z, a1.w};
        float wv[8] = {w0.x, w0.y, w0.z, w0.w, w1.x, w1.y, w1.z, w1.w};
        #pragma unroll
        for (int i = 0; i < 8; i++)
            #pragma unroll
            for (int j = 0; j < 8; j++)
                acc[i][j] = fmaf(av[i], wv[j], acc[i][j]);
    }
    __syncthreads();

    // ---- stage A phase 2: nf[src] rows (k 32..63) ----
    #pragma unroll
    for (int i = 0; i < 4; i++) {
        int c = c0 + i;
        float4 v = nreg[i];
        sA[(c * 4 + 0) * 128 + e] = v.x;
        sA[(c * 4 + 1) * 128 + e] = v.y;
        sA[(c * 4 + 2) * 128 + e] = v.z;
        sA[(c * 4 + 3) * 128 + e] = v.w;
    }
    __syncthreads();

    // ---- compute phase 2: k 32..63 (nf[src] @ Wni) ----
    #pragma unroll 4
    for (int k = 0; k < 32; k++) {
        float4 a0 = *(const float4*)(sA + k * 128 + e0);
        float4 a1 = *(const float4*)(sA + k * 128 + e0 + 4);
        float4 w0 = *(const float4*)(sW + (32 + k) * SWS + woff);
        float4 w1 = *(const float4*)(sW + (32 + k) * SWS + woff + 4);
        float av[8] = {a0.x, a0.y, a0.z, a0.w, a1.x, a1.y, a1.z, a1.w};
        float wv[8] = {w0.x, w0.y, w0.z, w0.w, w1.x, w1.y, w1.z, w1.w};
        #pragma unroll
        for (int i = 0; i < 8; i++)
            #pragma unroll
            for (int j = 0; j < 8; j++)
                acc[i][j] = fmaf(av[i], wv[j], acc[i][j]);
    }

    // ---- epilogue ----
    int h = jg >> 2;
    float atv[8];
    {
        const float* ap = attn + h * 32 + (jg & 3) * 8;
        float4 a0 = *(const float4*)(ap);
        float4 a1 = *(const float4*)(ap + 4);
        atv[0] = a0.x; atv[1] = a0.y; atv[2] = a0.z; atv[3] = a0.w;
        atv[4] = a1.x; atv[5] = a1.y; atv[6] = a1.z; atv[7] = a1.w;
    }
    float lg[8];
    #pragma unroll
    for (int i = 0; i < 8; i++) {
        int d = dst_p[e0b + e0 + i];
        const float* fr = f_nj + (size_t)d * 128 + j0;
        float4 f0 = *(const float4*)(fr);
        float4 f1 = *(const float4*)(fr + 4);
        float fv[8] = {f0.x, f0.y, f0.z, f0.w, f1.x, f1.y, f1.z, f1.w};
        float x[8];
        float lgh = 0.f;
        #pragma unroll
        for (int j = 0; j < 8; j++) {
            float v = acc[i][j] + fv[j];
            v = (v >= 0.f) ? v : 0.2f * v;
            x[j] = v;
            lgh = fmaf(v, atv[j], lgh);
        }
        lg[i] = lgh;
        if (WRITE_EF) {
            #pragma unroll
            for (int j = 0; j < 8; j++) {
                x[j] += __shfl_xor(x[j], 4);
                x[j] += __shfl_xor(x[j], 8);
            }
            if (jg < 4) {
                float* eo = ef_out + (size_t)(e0b + e0 + i) * 32 + jg * 8;
                *(float4*)(eo) = make_float4(x[0] * 0.25f, x[1] * 0.25f, x[2] * 0.25f, x[3] * 0.25f);
                *(float4*)(eo + 4) = make_float4(x[4] * 0.25f, x[5] * 0.25f, x[6] * 0.25f, x[7] * 0.25f);
            }
        }
    }
    #pragma unroll
    for (int i = 0; i < 8; i++) {
        lg[i] += __shfl_xor(lg[i], 1);
        lg[i] += __shfl_xor(lg[i], 2);
    }
    if ((jg & 3) == 0) {
        #pragma unroll
        for (int i = 0; i < 8; i++)
            logits[(size_t)(e0b + e0 + i) * 4 + h] = lg[i];
    }
}

// ---------------------------------------------------------------------------
// One wave per dst node; single pass (softmax is shift-invariant; logits are
// O(10) so raw exp is safe in fp32).
__global__ __launch_bounds__(256) void aggregate(
    const int* __restrict__ ro, const int* __restrict__ src_p,
    const float* __restrict__ logits,  // E x 4 (permuted)
    const float* __restrict__ nf_cur,  // N x 32
    float* __restrict__ agg) {         // N x 128
    int wid = (blockIdx.x * 256 + threadIdx.x) >> 6;
    int lane = threadIdx.x & 63;
    if (wid >= NNODE) return;
    int beg = ro[wid], end = ro[wid + 1];
    float* arow = agg + (size_t)wid * 128;
    if (beg == end) {
        arow[lane] = 0.f;
        arow[lane + 64] = 0.f;
        return;
    }
    int hA = lane >> 5;
    int k = lane & 31;
    float den1 = 0.f, den2 = 0.f, acc1 = 0.f, acc2 = 0.f;
    for (int i = beg; i < end; i++) {
        int s = src_p[i];
        float a1 = __expf(logits[(size_t)i * 4 + hA]);
        float a2 = __expf(logits[(size_t)i * 4 + hA + 2]);
        den1 += a1; den2 += a2;
        float v = nf_cur[(size_t)s * 32 + k];
        acc1 = fmaf(a1, v, acc1);
        acc2 = fmaf(a2, v, acc2);
    }
    arow[lane] = acc1 / den1;
    arow[lane + 64] = acc2 / den2;
}

// ---------------------------------------------------------------------------
// Node post kernel, wave-uniform LDS broadcast of W, TM=2 nodes/thread.
//  FIRST_GEMM: X = 0.25 * (agg[n] @ W1)  (written to nf_next)   [W1 from Wnode]
//  else:       X = Xin[n] (N x 32 rows, e.g. input nf)
//  WRITE_FNJ:  fnj_next[n] = X @ W2                              [W2 = Wnj slice]
// Block 256 threads -> 512 nodes; grid 196.
// ---------------------------------------------------------------------------
template <bool FIRST_GEMM, bool WRITE_FNJ>
__global__ __launch_bounds__(256) void post_v2(
    const float* __restrict__ Xin,     // agg (N x 128) if FIRST_GEMM else nf (N x 32)
    const float* __restrict__ Wnode,   // 32x128 layer slice (FIRST_GEMM)
    const float* __restrict__ Wnj_n,   // 32x128 slice (WRITE_FNJ)
    float* __restrict__ nf_next,       // N x 32 (FIRST_GEMM)
    float* __restrict__ fnj_next) {    // N x 128 (WRITE_FNJ)
    __shared__ float sW1[128 * 32];
    __shared__ float sW2[32 * 128];
    int t = threadIdx.x;

    if (FIRST_GEMM) {
        // sW1[k][d] = Wnode[(k&31)*128 + (k>>5)*32 + d], k = h*32+kk
        const float4* wsrc = (const float4*)Wnode;
        float4* wdst = (float4*)sW1;
        #pragma unroll
        for (int i = 0; i < 4; i++) {
            int f = t + i * 256;            // dest float4 idx 0..1023
            int k = f >> 3, dq = f & 7;
            wdst[f] = wsrc[(k & 31) * 32 + (k >> 5) * 8 + dq];
        }
    }
    if (WRITE_FNJ) {
        const float4* wsrc = (const float4*)Wnj_n;
        float4* wdst = (float4*)sW2;
        #pragma unroll
        for (int i = 0; i < 4; i++) {
            int f = t + i * 256;
            wdst[f] = wsrc[f];
        }
    }
    __syncthreads();

    int n0 = blockIdx.x * 512 + t;     // nodes n0 and n0+256
    int n1 = n0 + 256;
    bool v0 = n0 < NNODE, v1 = n1 < NNODE;
    float X0[32], X1[32];

    if (FIRST_GEMM) {
        #pragma unroll
        for (int d = 0; d < 32; d++) { X0[d] = 0.f; X1[d] = 0.f; }
        const float4* a0 = (const float4*)(Xin + (size_t)n0 * 128);
        const float4* a1 = (const float4*)(Xin + (size_t)n1 * 128);
        const float4* w1 = (const float4*)sW1;
        for (int kq = 0; kq < 32; kq++) {
            float4 q0 = v0 ? a0[kq] : make_float4(0.f, 0.f, 0.f, 0.f);
            float4 q1 = v1 ? a1[kq] : make_float4(0.f, 0.f, 0.f, 0.f);
            float av0[4] = {q0.x, q0.y, q0.z, q0.w};
            float av1[4] = {q1.x, q1.y, q1.z, q1.w};
            #pragma unroll
            for (int r = 0; r < 4; r++) {
                int k = kq * 4 + r;
                #pragma unroll
                for (int dq = 0; dq < 8; dq++) {
                    float4 w = w1[k * 8 + dq];
                    X0[dq * 4 + 0] = fmaf(av0[r], w.x, X0[dq * 4 + 0]);
                    X0[dq * 4 + 1] = fmaf(av0[r], w.y, X0[dq * 4 + 1]);
                    X0[dq * 4 + 2] = fmaf(av0[r], w.z, X0[dq * 4 + 2]);
                    X0[dq * 4 + 3] = fmaf(av0[r], w.w, X0[dq * 4 + 3]);
                    X1[dq * 4 + 0] = fmaf(av1[r], w.x, X1[dq * 4 + 0]);
                    X1[dq * 4 + 1] = fmaf(av1[r], w.y, X1[dq * 4 + 1]);
                    X1[dq * 4 + 2] = fmaf(av1[r], w.z, X1[dq * 4 + 2]);
                    X1[dq * 4 + 3] = fmaf(av1[r], w.w, X1[dq * 4 + 3]);
                }
            }
        }
        #pragma unroll
        for (int d = 0; d < 32; d++) { X0[d] *= 0.25f; X1[d] *= 0.25f; }
        if (v0) {
            float* o = nf_next + (size_t)n0 * 32;
            #pragma unroll
            for (int dq = 0; dq < 8; dq++)
                *(float4*)(o + dq * 4) = make_float4(X0[dq*4], X0[dq*4+1], X0[dq*4+2], X0[dq*4+3]);
        }
        if (v1) {
            float* o = nf_next + (size_t)n1 * 32;
            #pragma unroll
            for (int dq = 0; dq < 8; dq++)
                *(float4*)(o + dq * 4) = make_float4(X1[dq*4], X1[dq*4+1], X1[dq*4+2], X1[dq*4+3]);
        }
    } else {
        const float4* a0 = (const float4*)(Xin + (size_t)n0 * 32);
        const float4* a1 = (const float4*)(Xin + (size_t)n1 * 32);
        #pragma unroll
        for (int kq = 0; kq < 8; kq++) {
            float4 q0 = v0 ? a0[kq] : make_float4(0.f, 0.f, 0.f, 0.f);
            float4 q1 = v1 ? a1[kq] : make_float4(0.f, 0.f, 0.f, 0.f);
            X0[kq*4] = q0.x; X0[kq*4+1] = q0.y; X0[kq*4+2] = q0.z; X0[kq*4+3] = q0.w;
            X1[kq*4] = q1.x; X1[kq*4+1] = q1.y; X1[kq*4+2] = q1.z; X1[kq*4+3] = q1.w;
        }
    }

    if (WRITE_FNJ) {
        const float4* w2 = (const float4*)sW2;
        for (int jc = 0; jc < 16; jc++) {           // j chunk of 8
            float ac0[8], ac1[8];
            #pragma unroll
            for (int j = 0; j < 8; j++) { ac0[j] = 0.f; ac1[j] = 0.f; }
            #pragma unroll 8
            for (int k = 0; k < 32; k++) {
                float4 wa = w2[k * 32 + jc * 2];
                float4 wb = w2[k * 32 + jc * 2 + 1];
                float xv0 = X0[k], xv1 = X1[k];
                ac0[0] = fmaf(xv0, wa.x, ac0[0]); ac0[1] = fmaf(xv0, wa.y, ac0[1]);
                ac0[2] = fmaf(xv0, wa.z, ac0[2]); ac0[3] = fmaf(xv0, wa.w, ac0[3]);
                ac0[4] = fmaf(xv0, wb.x, ac0[4]); ac0[5] = fmaf(xv0, wb.y, ac0[5]);
                ac0[6] = fmaf(xv0, wb.z, ac0[6]); ac0[7] = fmaf(xv0, wb.w, ac0[7]);
                ac1[0] = fmaf(xv1, wa.x, ac1[0]); ac1[1] = fmaf(xv1, wa.y, ac1[1]);
                ac1[2] = fmaf(xv1, wa.z, ac1[2]); ac1[3] = fmaf(xv1, wa.w, ac1[3]);
                ac1[4] = fmaf(xv1, wb.x, ac1[4]); ac1[5] = fmaf(xv1, wb.y, ac1[5]);
                ac1[6] = fmaf(xv1, wb.z, ac1[6]); ac1[7] = fmaf(xv1, wb.w, ac1[7]);
            }
            if (v0) {
                float* o = fnj_next + (size_t)n0 * 128 + jc * 8;
                *(float4*)(o) = make_float4(ac0[0], ac0[1], ac0[2], ac0[3]);
                *(float4*)(o + 4) = make_float4(ac0[4], ac0[5], ac0[6], ac0[7]);
            }
            if (v1) {
                float* o = fnj_next + (size_t)n1 * 128 + jc * 8;
                *(float4*)(o) = make_float4(ac1[0], ac1[1], ac1[2], ac1[3]);
                *(float4*)(o + 4) = make_float4(ac1[4], ac1[5], ac1[6], ac1[7]);
            }
        }
    }
}

// ---------------------------------------------------------------------------
extern "C" void kernel_launch(void* const* d_in, const int* in_sizes, int n_in,
                              void* d_out, int out_size, void* d_ws, size_t ws_size,
                              hipStream_t stream) {
    const float* nf   = (const float*)d_in[0];
    const float* ef   = (const float*)d_in[1];
    const int*   src  = (const int*)d_in[2];
    const int*   dst  = (const int*)d_in[3];
    const float* Wni  = (const float*)d_in[4];
    const float* Wnj  = (const float*)d_in[5];
    const float* Wfij = (const float*)d_in[6];
    const float* Wnd  = (const float*)d_in[7];
    const float* attn = (const float*)d_in[8];
    const float* bias = (const float*)d_in[9];
    float* out = (float*)d_out;

    char* ws = (char*)d_ws;
    size_t off = 0;
    auto alloc = [&](size_t bytes) {
        void* p = ws + off;
        off += (bytes + 255) & ~(size_t)255;
        return p;
    };
    float* fnj    = (float*)alloc((size_t)NNODE * 128 * 4);
    float* agg    = (float*)alloc((size_t)NNODE * 128 * 4);
    float* efA    = (float*)alloc((size_t)NEDGE * 32 * 4);
    float* logits = (float*)alloc((size_t)NEDGE * 4 * 4);
    float* nfA    = (float*)alloc((size_t)NNODE * 32 * 4);
    float* nfB    = (float*)alloc((size_t)NNODE * 32 * 4);
    int*   counts = (int*)alloc((size_t)NNODE * 4);
    int*   cursor = (int*)alloc((size_t)NNODE * 4);
    int*   ro     = (int*)alloc((size_t)(NNODE + 1) * 4);
    int*   eidx   = (int*)alloc((size_t)NEDGE * 4);
    int*   src_p  = (int*)alloc((size_t)NEDGE * 4);
    int*   dst_p  = (int*)alloc((size_t)NEDGE * 4);
    int*   bsums  = (int*)alloc(1024 * 4);

    const int NB_E = (NEDGE + 255) / 256;          // 3125
    const int NB_N = (NNODE + 255) / 256;          // 391
    const int NB_AGG = (NNODE + 3) / 4;            // 25000
    const int NB_SCAN = (NNODE + 1023) / 1024;     // 98
    const int NB_ET = NEDGE / EB;                  // 6250
    const int NB_P  = (NNODE + 511) / 512;         // 196

    zero_ints<<<NB_N, 256, 0, stream>>>(counts, cursor, NNODE);
    count_dst<<<NB_E, 256, 0, stream>>>(dst, counts);
    scan_chunks<<<NB_SCAN, 256, 0, stream>>>(counts, ro, bsums, NNODE);
    scan_bsums<<<1, 256, 0, stream>>>(bsums, NB_SCAN);
    scan_add<<<NB_N, 256, 0, stream>>>(ro, bsums, NNODE);
    scatter_edges<<<NB_E, 256, 0, stream>>>(src, dst, ro, cursor, eidx, src_p, dst_p);

    // layer 0 f_nj = nf @ Wnj[0]
    post_v2<false, true><<<NB_P, 256, 0, stream>>>(nf, nullptr, Wnj, nullptr, fnj);

    // ----- layer 0 -----
    edge_tile_kernel<true, true><<<NB_ET, 256, 0, stream>>>(ef, eidx, src_p, dst_p, nf, fnj,
                                                            Wni, Wfij, attn, bias, logits, efA);
    aggregate<<<NB_AGG, 256, 0, stream>>>(ro, src_p, logits, nf, agg);
    post_v2<true, true><<<NB_P, 256, 0, stream>>>(agg, Wnd, Wnj + 4096, nfA, fnj);

    // ----- layer 1 -----
    edge_tile_kernel<true, false><<<NB_ET, 256, 0, stream>>>(efA, nullptr, src_p, dst_p, nfA, fnj,
                                                             Wni + 4096, Wfij + 4096, attn + 128,
                                                             bias + 128, logits, efA);
    aggregate<<<NB_AGG, 256, 0, stream>>>(ro, src_p, logits, nfA, agg);
    post_v2<true, true><<<NB_P, 256, 0, stream>>>(agg, Wnd + 4096, Wnj + 8192, nfB, fnj);

    // ----- layer 2 -----
    edge_tile_kernel<false, false><<<NB_ET, 256, 0, stream>>>(efA, nullptr, src_p, dst_p, nfB, fnj,
                                                              Wni + 8192, Wfij + 8192, attn + 256,
                                                              bias + 256, logits, nullptr);
    aggregate<<<NB_AGG, 256, 0, stream>>>(ro, src_p, logits, nfB, agg);
    post_v2<true, false><<<NB_P, 256, 0, stream>>>(agg, Wnd + 8192, nullptr, out, nullptr);
}

// Round 5
// 1089.309 us; speedup vs baseline: 2.6679x; 1.0497x over previous
//
#include <hip/hip_runtime.h>

#define NNODE 100000
#define NEDGE 800000
#define EB 128
#define SWS 140   // skewed W row stride in floats
// H = 4, D = 32, H*D = 128, DN = DE = 32, NL = 3

// ---------------------------------------------------------------------------
// CSR build kernels (dst-indexed), run once per call
// ---------------------------------------------------------------------------
__global__ __launch_bounds__(256) void zero_ints(int* __restrict__ a, int* __restrict__ b, int n) {
    int i = blockIdx.x * 256 + threadIdx.x;
    if (i < n) { a[i] = 0; b[i] = 0; }
}

__global__ __launch_bounds__(256) void count_dst(const int* __restrict__ dst, int* __restrict__ counts) {
    int e = blockIdx.x * 256 + threadIdx.x;
    if (e < NEDGE) atomicAdd(&counts[dst[e]], 1);
}

__global__ __launch_bounds__(256) void scan_chunks(const int* __restrict__ counts, int* __restrict__ ro,
                                                   int* __restrict__ bsums, int n) {
    __shared__ int sh[256];
    int base = blockIdx.x * 1024;
    int t = threadIdx.x;
    int v[4];
    int s = 0;
    #pragma unroll
    for (int i = 0; i < 4; i++) {
        int idx = base + t * 4 + i;
        int c = (idx < n) ? counts[idx] : 0;
        v[i] = s; s += c;
    }
    sh[t] = s; __syncthreads();
    for (int off = 1; off < 256; off <<= 1) {
        int x = 0;
        if (t >= off) x = sh[t - off];
        __syncthreads();
        if (t >= off) sh[t] += x;
        __syncthreads();
    }
    int thr_excl = (t > 0) ? sh[t - 1] : 0;
    #pragma unroll
    for (int i = 0; i < 4; i++) {
        int idx = base + t * 4 + i;
        if (idx < n) ro[idx] = thr_excl + v[i];
    }
    if (t == 255) bsums[blockIdx.x] = sh[255];
}

__global__ __launch_bounds__(256) void scan_bsums(int* __restrict__ bsums, int nb) {
    __shared__ int sh[256];
    int t = threadIdx.x;
    int val = (t < nb) ? bsums[t] : 0;
    sh[t] = val; __syncthreads();
    for (int off = 1; off < 256; off <<= 1) {
        int x = 0;
        if (t >= off) x = sh[t - off];
        __syncthreads();
        if (t >= off) sh[t] += x;
        __syncthreads();
    }
    int excl = (t > 0) ? sh[t - 1] : 0;
    if (t < nb) bsums[t] = excl;
}

__global__ __launch_bounds__(256) void scan_add(int* __restrict__ ro, const int* __restrict__ bsums, int n) {
    int i = blockIdx.x * 256 + threadIdx.x;
    if (i < n) ro[i] += bsums[i >> 10];
    if (i == 0) ro[n] = NEDGE;
}

__global__ __launch_bounds__(256) void scatter_edges(const int* __restrict__ src, const int* __restrict__ dst,
                                                     const int* __restrict__ ro, int* __restrict__ cursor,
                                                     int* __restrict__ eidx, int* __restrict__ src_p,
                                                     int* __restrict__ dst_p) {
    int e = blockIdx.x * 256 + threadIdx.x;
    if (e < NEDGE) {
        int d = dst[e];
        int pos = atomicAdd(&cursor[d], 1);
        int idx = ro[d] + pos;
        eidx[idx] = e;
        src_p[idx] = src[e];
        dst_p[idx] = d;
    }
}

// ---------------------------------------------------------------------------
// Tiled edge kernel: C[e][j] = sum_k A[e][k]*W[k][j], A = [ef | nf[src]], K=64
// Block: 128 edges x 128 j, 256 threads, 8x8 register tile.
// BOTH W and A are K-chunked (32-k chunks, re-staged mid-kernel):
// LDS = 32*140*4 (sW) + 32*128*4 (sA) = 33.5 KB -> 4 blocks/CU.
// Chunk-1 operands (Wni + nf[src]) prefetched into regs during phase-0 compute.
// ---------------------------------------------------------------------------
template <bool WRITE_EF, bool GATHER_EF>
__global__ __launch_bounds__(256, 4) void edge_tile_kernel(
    const float* __restrict__ ef_in,     // E x 32 (orig order if GATHER_EF else permuted)
    const int* __restrict__ eidx,        // permuted -> orig (GATHER_EF only)
    const int* __restrict__ src_p, const int* __restrict__ dst_p,
    const float* __restrict__ nf_cur,    // N x 32
    const float* __restrict__ f_nj,      // N x 128
    const float* __restrict__ Wni,       // 32x128 layer slice
    const float* __restrict__ Wf,        // 32x128 layer slice
    const float* __restrict__ attn,      // 4x32 layer slice
    const float* __restrict__ bias,      // 128 layer slice
    float* __restrict__ logits,          // E x 4 (permuted order)
    float* __restrict__ ef_out) {        // E x 32 (permuted order)
    __shared__ float sW[32 * SWS];       // current W k-chunk (skewed)
    __shared__ float sA[32 * 128];       // current A_T k-chunk [k][e]

    int t = threadIdx.x;
    int e0b = blockIdx.x * EB;
    int e = t & 127;
    int c0 = (t >> 7) * 4;   // 0 or 4 (which half of the 8 float4s of a row)

    const float4* wf4 = (const float4*)Wf;
    const float4* wn4 = (const float4*)Wni;

    // ---- chunk 0 loads: Wf + ef rows ----
    float4 wreg[4];
    #pragma unroll
    for (int i = 0; i < 4; i++) wreg[i] = wf4[t + i * 256];
    float4 areg[4];
    {
        long erow = GATHER_EF ? (long)eidx[e0b + e] : (long)(e0b + e);
        const float4* er = (const float4*)(ef_in + (size_t)erow * 32);
        #pragma unroll
        for (int i = 0; i < 4; i++) areg[i] = er[c0 + i];
    }
    int ssrc = src_p[e0b + e];

    // ---- write chunk 0 to LDS ----
    #pragma unroll
    for (int i = 0; i < 4; i++) {
        int f = t + i * 256;             // float4 index 0..1023
        int k = f >> 5, jq = f & 31;     // j = jq*4
        *(float4*)(sW + k * SWS + jq * 4 + 4 * (jq >> 3)) = wreg[i];
    }
    #pragma unroll
    for (int i = 0; i < 4; i++) {
        int c = c0 + i;                  // 0..7
        float4 v = areg[i];
        sA[(c * 4 + 0) * 128 + e] = v.x;
        sA[(c * 4 + 1) * 128 + e] = v.y;
        sA[(c * 4 + 2) * 128 + e] = v.z;
        sA[(c * 4 + 3) * 128 + e] = v.w;
    }
    __syncthreads();

    // ---- issue chunk 1 loads early (hidden under phase-0 compute) ----
    #pragma unroll
    for (int i = 0; i < 4; i++) wreg[i] = wn4[t + i * 256];
    {
        const float4* srow = (const float4*)(nf_cur + (size_t)ssrc * 32);
        #pragma unroll
        for (int i = 0; i < 4; i++) areg[i] = srow[c0 + i];
    }

    int jg = t & 15, eg = t >> 4;
    int j0 = jg * 8, e0 = eg * 8;
    int woff = jg * 8 + 4 * (jg >> 2);   // skewed base for this thread's 8 j's

    float bj[8];
    {
        float4 b0 = *(const float4*)(bias + j0);
        float4 b1 = *(const float4*)(bias + j0 + 4);
        bj[0] = b0.x; bj[1] = b0.y; bj[2] = b0.z; bj[3] = b0.w;
        bj[4] = b1.x; bj[5] = b1.y; bj[6] = b1.z; bj[7] = b1.w;
    }
    float acc[8][8];
    #pragma unroll
    for (int i = 0; i < 8; i++)
        #pragma unroll
        for (int j = 0; j < 8; j++) acc[i][j] = bj[j];

    // ---- compute phase 0: k 0..31 (ef @ Wf) ----
    #pragma unroll 4
    for (int k = 0; k < 32; k++) {
        float4 a0 = *(const float4*)(sA + k * 128 + e0);
        float4 a1 = *(const float4*)(sA + k * 128 + e0 + 4);
        float4 w0 = *(const float4*)(sW + k * SWS + woff);
        float4 w1 = *(const float4*)(sW + k * SWS + woff + 4);
        float av[8] = {a0.x, a0.y, a0.z, a0.w, a1.x, a1.y, a1.z, a1.w};
        float wv[8] = {w0.x, w0.y, w0.z, w0.w, w1.x, w1.y, w1.z, w1.w};
        #pragma unroll
        for (int i = 0; i < 8; i++)
            #pragma unroll
            for (int j = 0; j < 8; j++)
                acc[i][j] = fmaf(av[i], wv[j], acc[i][j]);
    }
    __syncthreads();

    // ---- write chunk 1 (Wni + nf[src]) ----
    #pragma unroll
    for (int i = 0; i < 4; i++) {
        int f = t + i * 256;
        int k = f >> 5, jq = f & 31;
        *(float4*)(sW + k * SWS + jq * 4 + 4 * (jq >> 3)) = wreg[i];
    }
    #pragma unroll
    for (int i = 0; i < 4; i++) {
        int c = c0 + i;
        float4 v = areg[i];
        sA[(c * 4 + 0) * 128 + e] = v.x;
        sA[(c * 4 + 1) * 128 + e] = v.y;
        sA[(c * 4 + 2) * 128 + e] = v.z;
        sA[(c * 4 + 3) * 128 + e] = v.w;
    }
    __syncthreads();

    // ---- compute phase 1: k 32..63 (nf[src] @ Wni) ----
    #pragma unroll 4
    for (int k = 0; k < 32; k++) {
        float4 a0 = *(const float4*)(sA + k * 128 + e0);
        float4 a1 = *(const float4*)(sA + k * 128 + e0 + 4);
        float4 w0 = *(const float4*)(sW + k * SWS + woff);
        float4 w1 = *(const float4*)(sW + k * SWS + woff + 4);
        float av[8] = {a0.x, a0.y, a0.z, a0.w, a1.x, a1.y, a1.z, a1.w};
        float wv[8] = {w0.x, w0.y, w0.z, w0.w, w1.x, w1.y, w1.z, w1.w};
        #pragma unroll
        for (int i = 0; i < 8; i++)
            #pragma unroll
            for (int j = 0; j < 8; j++)
                acc[i][j] = fmaf(av[i], wv[j], acc[i][j]);
    }

    // ---- epilogue ----
    int h = jg >> 2;
    float atv[8];
    {
        const float* ap = attn + h * 32 + (jg & 3) * 8;
        float4 a0 = *(const float4*)(ap);
        float4 a1 = *(const float4*)(ap + 4);
        atv[0] = a0.x; atv[1] = a0.y; atv[2] = a0.z; atv[3] = a0.w;
        atv[4] = a1.x; atv[5] = a1.y; atv[6] = a1.z; atv[7] = a1.w;
    }
    float lg[8];
    #pragma unroll
    for (int i = 0; i < 8; i++) {
        int d = dst_p[e0b + e0 + i];
        const float* fr = f_nj + (size_t)d * 128 + j0;
        float4 f0 = *(const float4*)(fr);
        float4 f1 = *(const float4*)(fr + 4);
        float fv[8] = {f0.x, f0.y, f0.z, f0.w, f1.x, f1.y, f1.z, f1.w};
        float x[8];
        float lgh = 0.f;
        #pragma unroll
        for (int j = 0; j < 8; j++) {
            float v = acc[i][j] + fv[j];
            v = (v >= 0.f) ? v : 0.2f * v;
            x[j] = v;
            lgh = fmaf(v, atv[j], lgh);
        }
        lg[i] = lgh;
        if (WRITE_EF) {
            #pragma unroll
            for (int j = 0; j < 8; j++) {
                x[j] += __shfl_xor(x[j], 4);
                x[j] += __shfl_xor(x[j], 8);
            }
            if (jg < 4) {
                float* eo = ef_out + (size_t)(e0b + e0 + i) * 32 + jg * 8;
                *(float4*)(eo) = make_float4(x[0] * 0.25f, x[1] * 0.25f, x[2] * 0.25f, x[3] * 0.25f);
                *(float4*)(eo + 4) = make_float4(x[4] * 0.25f, x[5] * 0.25f, x[6] * 0.25f, x[7] * 0.25f);
            }
        }
    }
    #pragma unroll
    for (int i = 0; i < 8; i++) {
        lg[i] += __shfl_xor(lg[i], 1);
        lg[i] += __shfl_xor(lg[i], 2);
    }
    if ((jg & 3) == 0) {
        #pragma unroll
        for (int i = 0; i < 8; i++)
            logits[(size_t)(e0b + e0 + i) * 4 + h] = lg[i];
    }
}

// ---------------------------------------------------------------------------
// One wave per dst node; single pass (softmax is shift-invariant; logits are
// O(10) so raw exp is safe in fp32).
__global__ __launch_bounds__(256) void aggregate(
    const int* __restrict__ ro, const int* __restrict__ src_p,
    const float* __restrict__ logits,  // E x 4 (permuted)
    const float* __restrict__ nf_cur,  // N x 32
    float* __restrict__ agg) {         // N x 128
    int wid = (blockIdx.x * 256 + threadIdx.x) >> 6;
    int lane = threadIdx.x & 63;
    if (wid >= NNODE) return;
    int beg = ro[wid], end = ro[wid + 1];
    float* arow = agg + (size_t)wid * 128;
    if (beg == end) {
        arow[lane] = 0.f;
        arow[lane + 64] = 0.f;
        return;
    }
    int hA = lane >> 5;
    int k = lane & 31;
    float den1 = 0.f, den2 = 0.f, acc1 = 0.f, acc2 = 0.f;
    for (int i = beg; i < end; i++) {
        int s = src_p[i];
        float a1 = __expf(logits[(size_t)i * 4 + hA]);
        float a2 = __expf(logits[(size_t)i * 4 + hA + 2]);
        den1 += a1; den2 += a2;
        float v = nf_cur[(size_t)s * 32 + k];
        acc1 = fmaf(a1, v, acc1);
        acc2 = fmaf(a2, v, acc2);
    }
    arow[lane] = acc1 / den1;
    arow[lane + 64] = acc2 / den2;
}

// ---------------------------------------------------------------------------
// Node post kernel, wave-uniform LDS broadcast of W, 1 node/thread, grid 391.
//  FIRST_GEMM: X = 0.25 * (agg[n] @ W1)  (written to nf_next)   [W1 from Wnode]
//  else:       X = Xin[n] (N x 32 rows, e.g. input nf)
//  WRITE_FNJ:  fnj_next[n] = X @ W2                              [W2 = Wnj slice]
// ---------------------------------------------------------------------------
template <bool FIRST_GEMM, bool WRITE_FNJ>
__global__ __launch_bounds__(256) void post_v2(
    const float* __restrict__ Xin,     // agg (N x 128) if FIRST_GEMM else nf (N x 32)
    const float* __restrict__ Wnode,   // 32x128 layer slice (FIRST_GEMM)
    const float* __restrict__ Wnj_n,   // 32x128 slice (WRITE_FNJ)
    float* __restrict__ nf_next,       // N x 32 (FIRST_GEMM)
    float* __restrict__ fnj_next) {    // N x 128 (WRITE_FNJ)
    __shared__ float sW1[128 * 32];
    __shared__ float sW2[32 * 128];
    int t = threadIdx.x;

    if (FIRST_GEMM) {
        // sW1[k][d] = Wnode[(k&31)*128 + (k>>5)*32 + d], k = h*32+kk
        const float4* wsrc = (const float4*)Wnode;
        float4* wdst = (float4*)sW1;
        #pragma unroll
        for (int i = 0; i < 4; i++) {
            int f = t + i * 256;            // dest float4 idx 0..1023
            int k = f >> 3, dq = f & 7;
            wdst[f] = wsrc[(k & 31) * 32 + (k >> 5) * 8 + dq];
        }
    }
    if (WRITE_FNJ) {
        const float4* wsrc = (const float4*)Wnj_n;
        float4* wdst = (float4*)sW2;
        #pragma unroll
        for (int i = 0; i < 4; i++) {
            int f = t + i * 256;
            wdst[f] = wsrc[f];
        }
    }
    __syncthreads();

    int n0 = blockIdx.x * 256 + t;
    bool v0 = n0 < NNODE;
    float X0[32];

    if (FIRST_GEMM) {
        #pragma unroll
        for (int d = 0; d < 32; d++) X0[d] = 0.f;
        const float4* a0 = (const float4*)(Xin + (size_t)n0 * 128);
        const float4* w1 = (const float4*)sW1;
        for (int kq = 0; kq < 32; kq++) {
            float4 q0 = v0 ? a0[kq] : make_float4(0.f, 0.f, 0.f, 0.f);
            float av0[4] = {q0.x, q0.y, q0.z, q0.w};
            #pragma unroll
            for (int r = 0; r < 4; r++) {
                int k = kq * 4 + r;
                #pragma unroll
                for (int dq = 0; dq < 8; dq++) {
                    float4 w = w1[k * 8 + dq];
                    X0[dq * 4 + 0] = fmaf(av0[r], w.x, X0[dq * 4 + 0]);
                    X0[dq * 4 + 1] = fmaf(av0[r], w.y, X0[dq * 4 + 1]);
                    X0[dq * 4 + 2] = fmaf(av0[r], w.z, X0[dq * 4 + 2]);
                    X0[dq * 4 + 3] = fmaf(av0[r], w.w, X0[dq * 4 + 3]);
                }
            }
        }
        #pragma unroll
        for (int d = 0; d < 32; d++) X0[d] *= 0.25f;
        if (v0) {
            float* o = nf_next + (size_t)n0 * 32;
            #pragma unroll
            for (int dq = 0; dq < 8; dq++)
                *(float4*)(o + dq * 4) = make_float4(X0[dq*4], X0[dq*4+1], X0[dq*4+2], X0[dq*4+3]);
        }
    } else {
        const float4* a0 = (const float4*)(Xin + (size_t)n0 * 32);
        #pragma unroll
        for (int kq = 0; kq < 8; kq++) {
            float4 q0 = v0 ? a0[kq] : make_float4(0.f, 0.f, 0.f, 0.f);
            X0[kq*4] = q0.x; X0[kq*4+1] = q0.y; X0[kq*4+2] = q0.z; X0[kq*4+3] = q0.w;
        }
    }

    if (WRITE_FNJ) {
        const float4* w2 = (const float4*)sW2;
        for (int jc = 0; jc < 16; jc++) {           // j chunk of 8
            float ac0[8];
            #pragma unroll
            for (int j = 0; j < 8; j++) ac0[j] = 0.f;
            #pragma unroll 8
            for (int k = 0; k < 32; k++) {
                float4 wa = w2[k * 32 + jc * 2];
                float4 wb = w2[k * 32 + jc * 2 + 1];
                float xv0 = X0[k];
                ac0[0] = fmaf(xv0, wa.x, ac0[0]); ac0[1] = fmaf(xv0, wa.y, ac0[1]);
                ac0[2] = fmaf(xv0, wa.z, ac0[2]); ac0[3] = fmaf(xv0, wa.w, ac0[3]);
                ac0[4] = fmaf(xv0, wb.x, ac0[4]); ac0[5] = fmaf(xv0, wb.y, ac0[5]);
                ac0[6] = fmaf(xv0, wb.z, ac0[6]); ac0[7] = fmaf(xv0, wb.w, ac0[7]);
            }
            if (v0) {
                float* o = fnj_next + (size_t)n0 * 128 + jc * 8;
                *(float4*)(o) = make_float4(ac0[0], ac0[1], ac0[2], ac0[3]);
                *(float4*)(o + 4) = make_float4(ac0[4], ac0[5], ac0[6], ac0[7]);
            }
        }
    }
}

// ---------------------------------------------------------------------------
extern "C" void kernel_launch(void* const* d_in, const int* in_sizes, int n_in,
                              void* d_out, int out_size, void* d_ws, size_t ws_size,
                              hipStream_t stream) {
    const float* nf   = (const float*)d_in[0];
    const float* ef   = (const float*)d_in[1];
    const int*   src  = (const int*)d_in[2];
    const int*   dst  = (const int*)d_in[3];
    const float* Wni  = (const float*)d_in[4];
    const float* Wnj  = (const float*)d_in[5];
    const float* Wfij = (const float*)d_in[6];
    const float* Wnd  = (const float*)d_in[7];
    const float* attn = (const float*)d_in[8];
    const float* bias = (const float*)d_in[9];
    float* out = (float*)d_out;

    char* ws = (char*)d_ws;
    size_t off = 0;
    auto alloc = [&](size_t bytes) {
        void* p = ws + off;
        off += (bytes + 255) & ~(size_t)255;
        return p;
    };
    float* fnj    = (float*)alloc((size_t)NNODE * 128 * 4);
    float* agg    = (float*)alloc((size_t)NNODE * 128 * 4);
    float* efA    = (float*)alloc((size_t)NEDGE * 32 * 4);
    float* logits = (float*)alloc((size_t)NEDGE * 4 * 4);
    float* nfA    = (float*)alloc((size_t)NNODE * 32 * 4);
    float* nfB    = (float*)alloc((size_t)NNODE * 32 * 4);
    int*   counts = (int*)alloc((size_t)NNODE * 4);
    int*   cursor = (int*)alloc((size_t)NNODE * 4);
    int*   ro     = (int*)alloc((size_t)(NNODE + 1) * 4);
    int*   eidx   = (int*)alloc((size_t)NEDGE * 4);
    int*   src_p  = (int*)alloc((size_t)NEDGE * 4);
    int*   dst_p  = (int*)alloc((size_t)NEDGE * 4);
    int*   bsums  = (int*)alloc(1024 * 4);

    const int NB_E = (NEDGE + 255) / 256;          // 3125
    const int NB_N = (NNODE + 255) / 256;          // 391
    const int NB_AGG = (NNODE + 3) / 4;            // 25000
    const int NB_SCAN = (NNODE + 1023) / 1024;     // 98
    const int NB_ET = NEDGE / EB;                  // 6250
    const int NB_P  = (NNODE + 255) / 256;         // 391

    zero_ints<<<NB_N, 256, 0, stream>>>(counts, cursor, NNODE);
    count_dst<<<NB_E, 256, 0, stream>>>(dst, counts);
    scan_chunks<<<NB_SCAN, 256, 0, stream>>>(counts, ro, bsums, NNODE);
    scan_bsums<<<1, 256, 0, stream>>>(bsums, NB_SCAN);
    scan_add<<<NB_N, 256, 0, stream>>>(ro, bsums, NNODE);
    scatter_edges<<<NB_E, 256, 0, stream>>>(src, dst, ro, cursor, eidx, src_p, dst_p);

    // layer 0 f_nj = nf @ Wnj[0]
    post_v2<false, true><<<NB_P, 256, 0, stream>>>(nf, nullptr, Wnj, nullptr, fnj);

    // ----- layer 0 -----
    edge_tile_kernel<true, true><<<NB_ET, 256, 0, stream>>>(ef, eidx, src_p, dst_p, nf, fnj,
                                                            Wni, Wfij, attn, bias, logits, efA);
    aggregate<<<NB_AGG, 256, 0, stream>>>(ro, src_p, logits, nf, agg);
    post_v2<true, true><<<NB_P, 256, 0, stream>>>(agg, Wnd, Wnj + 4096, nfA, fnj);

    // ----- layer 1 -----
    edge_tile_kernel<true, false><<<NB_ET, 256, 0, stream>>>(efA, nullptr, src_p, dst_p, nfA, fnj,
                                                             Wni + 4096, Wfij + 4096, attn + 128,
                                                             bias + 128, logits, efA);
    aggregate<<<NB_AGG, 256, 0, stream>>>(ro, src_p, logits, nfA, agg);
    post_v2<true, true><<<NB_P, 256, 0, stream>>>(agg, Wnd + 4096, Wnj + 8192, nfB, fnj);

    // ----- layer 2 -----
    edge_tile_kernel<false, false><<<NB_ET, 256, 0, stream>>>(efA, nullptr, src_p, dst_p, nfB, fnj,
                                                              Wni + 8192, Wfij + 8192, attn + 256,
                                                              bias + 256, logits, nullptr);
    aggregate<<<NB_AGG, 256, 0, stream>>>(ro, src_p, logits, nfB, agg);
    post_v2<true, false><<<NB_P, 256, 0, stream>>>(agg, Wnd + 8192, nullptr, out, nullptr);
}